// Round 2
// baseline (1107.310 us; speedup 1.0000x reference)
//
#include <hip/hip_runtime.h>
#include <math.h>

#define B_   2
#define L_   1024
#define DM_  1024
#define DI_  2048
#define NS_  16
#define DTR_ 64
#define M_   (B_ * L_)          // 2048 rows
#define XZW_ (2 * DI_)          // 4096
#define XDW_ 128                // padded x_proj output width (dt|B|C|pad)

// ---------------- LayerNorm ----------------
__global__ __launch_bounds__(256) void ln_kernel(
    const float* __restrict__ x, const float* __restrict__ g,
    const float* __restrict__ b, float* __restrict__ xn)
{
  int r = blockIdx.x;
  int t = threadIdx.x;
  const float4* xr = (const float4*)(x + (size_t)r * DM_);
  float4 v = xr[t];
  float s  = v.x + v.y + v.z + v.w;
  float ss = v.x * v.x + v.y * v.y + v.z * v.z + v.w * v.w;
  for (int m = 32; m >= 1; m >>= 1) {
    s  += __shfl_down(s, m);
    ss += __shfl_down(ss, m);
  }
  __shared__ float sb[4], ssb[4];
  int w = t >> 6, lane = t & 63;
  if (lane == 0) { sb[w] = s; ssb[w] = ss; }
  __syncthreads();
  s  = sb[0] + sb[1] + sb[2] + sb[3];
  ss = ssb[0] + ssb[1] + ssb[2] + ssb[3];
  float mu  = s * (1.f / DM_);
  float var = ss * (1.f / DM_) - mu * mu;
  float rs  = rsqrtf(var + 1e-5f);
  float4 gv = ((const float4*)g)[t];
  float4 bv = ((const float4*)b)[t];
  float4 o;
  o.x = (v.x - mu) * rs * gv.x + bv.x;
  o.y = (v.y - mu) * rs * gv.y + bv.y;
  o.z = (v.z - mu) * rs * gv.z + bv.z;
  o.w = (v.w - mu) * rs * gv.w + bv.w;
  ((float4*)(xn + (size_t)r * DM_))[t] = o;
}

// ---------------- Generic tiled NT GEMM: C[m,n] = sum_k A[m,k]*Bw[n,k] ----------------
// mode 0: store acc
// mode 1: store softplus(acc + bias[n])
// mode 2: store acc + res[m*ldres + n]
#define BM 64
#define BN 64
#define BK 32
#define PADR 68   // K-major row length (floats); 68*4B = 272B = 17*16B -> b128-aligned rows

__global__ __launch_bounds__(256) void gemm_nt(
    const float* __restrict__ A, int lda,
    const float* __restrict__ Bw, int ldb,
    float* __restrict__ C, int ldc,
    int Mrows, int Ncols, int Kdim,
    int mode, const float* __restrict__ bias,
    const float* __restrict__ res, int ldres)
{
  __shared__ float as[BK][PADR];
  __shared__ float bs[BK][PADR];
  int bm = blockIdx.y * BM;
  int bn = blockIdx.x * BN;
  int t  = threadIdx.x;
  int tx = t & 15, ty = t >> 4;

  float acc[4][4] = {};

  int m0 = t >> 3;       // 0..31
  int kq = t & 7;        // float4 index within BK

  for (int k0 = 0; k0 < Kdim; k0 += BK) {
    // stage A (64x32) and B (64x32), transposed to K-major in LDS
    float4 a0 = *(const float4*)(A + (size_t)(bm + m0) * lda + k0 + kq * 4);
    float4 a1 = *(const float4*)(A + (size_t)(bm + m0 + 32) * lda + k0 + kq * 4);
    float4 b0 = *(const float4*)(Bw + (size_t)(bn + m0) * ldb + k0 + kq * 4);
    float4 b1 = *(const float4*)(Bw + (size_t)(bn + m0 + 32) * ldb + k0 + kq * 4);
    as[kq * 4 + 0][m0] = a0.x;  as[kq * 4 + 1][m0] = a0.y;
    as[kq * 4 + 2][m0] = a0.z;  as[kq * 4 + 3][m0] = a0.w;
    as[kq * 4 + 0][m0 + 32] = a1.x;  as[kq * 4 + 1][m0 + 32] = a1.y;
    as[kq * 4 + 2][m0 + 32] = a1.z;  as[kq * 4 + 3][m0 + 32] = a1.w;
    bs[kq * 4 + 0][m0] = b0.x;  bs[kq * 4 + 1][m0] = b0.y;
    bs[kq * 4 + 2][m0] = b0.z;  bs[kq * 4 + 3][m0] = b0.w;
    bs[kq * 4 + 0][m0 + 32] = b1.x;  bs[kq * 4 + 1][m0 + 32] = b1.y;
    bs[kq * 4 + 2][m0 + 32] = b1.z;  bs[kq * 4 + 3][m0 + 32] = b1.w;
    __syncthreads();

#pragma unroll
    for (int kk = 0; kk < BK; ++kk) {
      float4 a4 = *(const float4*)&as[kk][ty * 4];
      float4 b4 = *(const float4*)&bs[kk][tx * 4];
      float ar[4] = {a4.x, a4.y, a4.z, a4.w};
      float br[4] = {b4.x, b4.y, b4.z, b4.w};
#pragma unroll
      for (int i = 0; i < 4; ++i)
#pragma unroll
        for (int j = 0; j < 4; ++j)
          acc[i][j] = fmaf(ar[i], br[j], acc[i][j]);
    }
    __syncthreads();
  }

#pragma unroll
  for (int i = 0; i < 4; ++i) {
    int r = bm + ty * 4 + i;
    int c = bn + tx * 4;
    float4 o;
    float vv[4];
#pragma unroll
    for (int j = 0; j < 4; ++j) {
      float v = acc[i][j];
      if (mode == 1) {
        v += bias[c + j];
        v = (v > 20.f) ? v : log1pf(expf(v));
      } else if (mode == 2) {
        v += res[(size_t)r * ldres + c + j];
      }
      vv[j] = v;
    }
    o.x = vv[0]; o.y = vv[1]; o.z = vv[2]; o.w = vv[3];
    *(float4*)(C + (size_t)r * ldc + c) = o;
  }
}

// ---------------- pad x_proj_w (96x2048) -> (128x2048 zero-padded) ----------------
__global__ __launch_bounds__(256) void pad_w_kernel(
    const float* __restrict__ xw, float* __restrict__ wpad)
{
  int i = blockIdx.x * 256 + threadIdx.x;   // over 128*2048
  int r = i >> 11;
  wpad[i] = (r < 96) ? xw[i] : 0.f;
}

// ---------------- depthwise causal conv (K=4) + SiLU ----------------
#define LCH 128
__global__ __launch_bounds__(256) void conv_silu_kernel(
    const float* __restrict__ xz, const float* __restrict__ cw,
    const float* __restrict__ cb, float* __restrict__ u)
{
  int d  = blockIdx.x * 256 + threadIdx.x;  // channel
  int l0 = blockIdx.y * LCH;
  int b  = blockIdx.z;
  float w0 = cw[d * 4 + 0], w1 = cw[d * 4 + 1];
  float w2 = cw[d * 4 + 2], w3 = cw[d * 4 + 3];
  float bias = cb[d];
  const float* xi = xz + (size_t)(b * L_) * XZW_ + d;
  float x3 = (l0 >= 3) ? xi[(size_t)(l0 - 3) * XZW_] : 0.f;
  float x2 = (l0 >= 2) ? xi[(size_t)(l0 - 2) * XZW_] : 0.f;
  float x1 = (l0 >= 1) ? xi[(size_t)(l0 - 1) * XZW_] : 0.f;
  for (int l = l0; l < l0 + LCH; ++l) {
    float x0 = xi[(size_t)l * XZW_];
    float v = w0 * x3 + w1 * x2 + w2 * x1 + w3 * x0 + bias;
    float uu = v / (1.f + expf(-v));
    u[((size_t)(b * L_) + l) * DI_ + d] = uu;
    x3 = x2; x2 = x1; x1 = x0;
  }
}

// ---------------- selective scan ----------------
// thread = (channel_local, n); block = 16 channels; grid = (DI/16, B)
__global__ __launch_bounds__(256) void scan_kernel(
    const float* __restrict__ delta, const float* __restrict__ u,
    const float* __restrict__ xdbl, const float* __restrict__ A_log,
    float* __restrict__ y)
{
  int t = threadIdx.x;
  int n  = t & 15;
  int cl = t >> 4;                        // 0..15
  int d  = blockIdx.x * 16 + cl;
  int b  = blockIdx.y;
  float Adn = -expf(A_log[d * NS_ + n]);
  float h = 0.f;
  const float* dptr = delta + (size_t)b * L_ * DI_ + d;
  const float* uptr = u     + (size_t)b * L_ * DI_ + d;
  const float* xptr = xdbl  + (size_t)b * L_ * XDW_;
  float* yptr       = y     + (size_t)b * L_ * DI_ + d;
  for (int l = 0; l < L_; ++l) {
    float dv = dptr[(size_t)l * DI_];
    float uv = uptr[(size_t)l * DI_];
    float Bv = xptr[l * XDW_ + DTR_ + n];
    float Cv = xptr[l * XDW_ + DTR_ + NS_ + n];
    float dA = expf(dv * Adn);
    h = dA * h + dv * Bv * uv;
    float py = h * Cv;
    py += __shfl_xor(py, 1);
    py += __shfl_xor(py, 2);
    py += __shfl_xor(py, 4);
    py += __shfl_xor(py, 8);
    if (n == 0) yptr[(size_t)l * DI_] = py;
  }
}

// ---------------- y = (y_scan + u*D) * silu(z) ----------------
__global__ __launch_bounds__(256) void ymod_kernel(
    float* __restrict__ y, const float* __restrict__ u,
    const float* __restrict__ xz, const float* __restrict__ Dp)
{
  int i = blockIdx.x * 256 + threadIdx.x;   // float4 index over M_*DI_/4
  int row = i >> 9;                         // DI_/4 = 512
  int c4  = i & 511;
  float4 yv = ((float4*)y)[i];
  float4 uv = ((const float4*)u)[i];
  float4 zv = *(const float4*)(xz + (size_t)row * XZW_ + DI_ + c4 * 4);
  float4 dv = ((const float4*)Dp)[c4];
  float4 o;
  float zs;
  zs = zv.x / (1.f + expf(-zv.x)); o.x = (yv.x + uv.x * dv.x) * zs;
  zs = zv.y / (1.f + expf(-zv.y)); o.y = (yv.y + uv.y * dv.y) * zs;
  zs = zv.z / (1.f + expf(-zv.z)); o.z = (yv.z + uv.z * dv.z) * zs;
  zs = zv.w / (1.f + expf(-zv.w)); o.w = (yv.w + uv.w * dv.w) * zs;
  ((float4*)y)[i] = o;
}

extern "C" void kernel_launch(void* const* d_in, const int* in_sizes, int n_in,
                              void* d_out, int out_size, void* d_ws, size_t ws_size,
                              hipStream_t stream)
{
  const float* x         = (const float*)d_in[0];
  const float* ln_g      = (const float*)d_in[1];
  const float* ln_b      = (const float*)d_in[2];
  const float* in_proj_w = (const float*)d_in[3];
  const float* conv_w    = (const float*)d_in[4];
  const float* conv_b    = (const float*)d_in[5];
  const float* x_proj_w  = (const float*)d_in[6];
  const float* dt_proj_w = (const float*)d_in[7];
  const float* dt_proj_b = (const float*)d_in[8];
  const float* A_log     = (const float*)d_in[9];
  const float* Dp        = (const float*)d_in[10];
  const float* out_proj_w= (const float*)d_in[11];
  float* out = (float*)d_out;

  float* ws   = (float*)d_ws;
  float* xn   = ws;                       // 2048*1024     = 2,097,152
  float* xz   = ws + 2097152;             // 2048*4096     = 8,388,608
  float* u    = ws + 10485760;            // 2048*2048     = 4,194,304
  float* xdbl = ws + 14680064;            // 2048*128      =   262,144
  float* dlt  = ws + 14942208;            // 2048*2048     = 4,194,304
  float* y    = ws + 19136512;            // 2048*2048     = 4,194,304
  float* wpad = ws + 23330816;            // 128*2048      =   262,144

  // 1. LayerNorm
  ln_kernel<<<M_, 256, 0, stream>>>(x, ln_g, ln_b, xn);

  // 2. in_proj: xz = xn @ in_proj_w^T   (2048x1024 * 4096x1024^T)
  gemm_nt<<<dim3(XZW_ / BN, M_ / BM), 256, 0, stream>>>(
      xn, DM_, in_proj_w, DM_, xz, XZW_, M_, XZW_, DM_, 0, nullptr, nullptr, 0);

  // 3. pad x_proj_w
  pad_w_kernel<<<(XDW_ * DI_) / 256, 256, 0, stream>>>(x_proj_w, wpad);

  // 4. conv + silu -> u
  conv_silu_kernel<<<dim3(DI_ / 256, L_ / LCH, B_), 256, 0, stream>>>(
      xz, conv_w, conv_b, u);

  // 5. x_proj: xdbl = u @ wpad^T   (2048x2048 * 128x2048^T)
  gemm_nt<<<dim3(XDW_ / BN, M_ / BM), 256, 0, stream>>>(
      u, DI_, wpad, DI_, xdbl, XDW_, M_, XDW_, DI_, 0, nullptr, nullptr, 0);

  // 6. dt_proj + softplus: dlt = softplus(xdbl[:, :64] @ dt_proj_w^T + b)
  gemm_nt<<<dim3(DI_ / BN, M_ / BM), 256, 0, stream>>>(
      xdbl, XDW_, dt_proj_w, DTR_, dlt, DI_, M_, DI_, DTR_, 1, dt_proj_b, nullptr, 0);

  // 7. selective scan -> y
  scan_kernel<<<dim3(DI_ / 16, B_), 256, 0, stream>>>(dlt, u, xdbl, A_log, y);

  // 8. y = (y + u*D) * silu(z)
  ymod_kernel<<<(M_ * DI_ / 4) / 256, 256, 0, stream>>>(y, u, xz, Dp);

  // 9. out_proj + residual: out = x + y @ out_proj_w^T  (2048x2048 * 1024x2048^T)
  gemm_nt<<<dim3(DM_ / BN, M_ / BM), 256, 0, stream>>>(
      y, DI_, out_proj_w, DI_, out, DM_, M_, DM_, DI_, 2, nullptr, x, DM_);
}

// Round 4
// 487.996 us; speedup vs baseline: 2.2691x; 2.2691x over previous
//
#include <hip/hip_runtime.h>
#include <hip/hip_bf16.h>
#include <math.h>

#define B_   2
#define L_   1024
#define DM_  1024
#define DI_  2048
#define NS_  16
#define DTR_ 64
#define M_   (B_ * L_)          // 2048 rows
#define XZW_ (2 * DI_)          // 4096
#define XDW_ 128                // padded x_proj output width (dt|B|C|pad)
#define CH_  8                  // scan chunks
#define CLEN_ (L_ / CH_)        // 128

typedef __attribute__((ext_vector_type(8))) short bf16x8;
typedef __attribute__((ext_vector_type(4))) float f32x4;
typedef __attribute__((ext_vector_type(4))) unsigned short u16x4;

static __device__ __forceinline__ unsigned short f2bf(float f) {
  __hip_bfloat16 h = __float2bfloat16(f);
  return *reinterpret_cast<unsigned short*>(&h);
}

// ---------------- LayerNorm -> bf16 ----------------
__global__ __launch_bounds__(256) void ln_kernel(
    const float* __restrict__ x, const float* __restrict__ g,
    const float* __restrict__ b, unsigned short* __restrict__ xnb)
{
  int r = blockIdx.x;
  int t = threadIdx.x;
  const float4* xr = (const float4*)(x + (size_t)r * DM_);
  float4 v = xr[t];
  float s  = v.x + v.y + v.z + v.w;
  float ss = v.x * v.x + v.y * v.y + v.z * v.z + v.w * v.w;
  for (int m = 32; m >= 1; m >>= 1) {
    s  += __shfl_down(s, m);
    ss += __shfl_down(ss, m);
  }
  __shared__ float sb[4], ssb[4];
  int w = t >> 6, lane = t & 63;
  if (lane == 0) { sb[w] = s; ssb[w] = ss; }
  __syncthreads();
  s  = sb[0] + sb[1] + sb[2] + sb[3];
  ss = ssb[0] + ssb[1] + ssb[2] + ssb[3];
  float mu  = s * (1.f / DM_);
  float var = ss * (1.f / DM_) - mu * mu;
  float rs  = rsqrtf(var + 1e-5f);
  float4 gv = ((const float4*)g)[t];
  float4 bv = ((const float4*)b)[t];
  u16x4 o;
  o[0] = f2bf((v.x - mu) * rs * gv.x + bv.x);
  o[1] = f2bf((v.y - mu) * rs * gv.y + bv.y);
  o[2] = f2bf((v.z - mu) * rs * gv.z + bv.z);
  o[3] = f2bf((v.w - mu) * rs * gv.w + bv.w);
  ((u16x4*)xnb)[r * 256 + t] = o;
}

// ---------------- fp32 -> bf16 bulk convert (n4 float4 groups) ----------------
__global__ __launch_bounds__(256) void f2bf_kernel(
    const float4* __restrict__ in, u16x4* __restrict__ outp)
{
  int i = blockIdx.x * 256 + threadIdx.x;
  float4 v = in[i];
  u16x4 o;
  o[0] = f2bf(v.x); o[1] = f2bf(v.y); o[2] = f2bf(v.z); o[3] = f2bf(v.w);
  outp[i] = o;
}

// ---------------- bf16 MFMA GEMM NT: C[m,n] = sum_k A[m,k]*Bw[n,k] ----------------
// 128x128 tile, BK=64, 4 waves each computing a 64x64 quadrant of 4x4 16x16 frags.
// LDS layout: [128 rows][8 kwords of 16B], XOR-swizzled: LDS[row][c] holds
// k-word (c ^ (row&7)). Staging achieves this with linear LDS dest (required by
// global_load_lds) + pre-swizzled per-lane GLOBAL source address.
// MODE 0: store acc ; MODE 2: store acc + res[row*ldres+col]
template<int MODE>
__global__ __launch_bounds__(256) void gemm_mfma(
    const short* __restrict__ A, int lda,
    const short* __restrict__ Bw, int ldb,
    float* __restrict__ C, int ldc, int Kdim,
    const float* __restrict__ res, int ldres)
{
  __shared__ __align__(16) short As[128 * 64];
  __shared__ __align__(16) short Bs[128 * 64];
  const int bm = blockIdx.y * 128, bn = blockIdx.x * 128;
  const int t = threadIdx.x, wid = t >> 6, lane = t & 63;
  const int wr = wid >> 1, wc = wid & 1;    // wave quadrant (wr*64, wc*64)

  f32x4 acc[4][4];
#pragma unroll
  for (int i = 0; i < 4; ++i)
#pragma unroll
    for (int j = 0; j < 4; ++j) acc[i][j] = (f32x4){0.f, 0.f, 0.f, 0.f};

  // staging-lane constants: per call, wave wid covers 8 rows (1024B)
  const int srow = wid * 8 + (lane >> 3);   // row within 32-row group
  const int sc   = lane & 7;                // linear k-word slot this lane fills

  const int r16 = lane & 15, khalf = lane >> 4;   // fragment addressing

  for (int k0 = 0; k0 < Kdim; k0 += 64) {
#pragma unroll
    for (int q = 0; q < 4; ++q) {
      int row = q * 32 + srow;
      int csw = sc ^ (row & 7);             // source k-word for this linear slot
      const short* gA = A + (size_t)(bm + row) * lda + k0 + csw * 8;
      const short* gB = Bw + (size_t)(bn + row) * ldb + k0 + csw * 8;
      __builtin_amdgcn_global_load_lds(
          (const __attribute__((address_space(1))) void*)gA,
          (__attribute__((address_space(3))) void*)(As + q * 2048 + wid * 512),
          16, 0, 0);
      __builtin_amdgcn_global_load_lds(
          (const __attribute__((address_space(1))) void*)gB,
          (__attribute__((address_space(3))) void*)(Bs + q * 2048 + wid * 512),
          16, 0, 0);
    }
    __syncthreads();

    bf16x8 af[4][2], bf[4][2];
#pragma unroll
    for (int m = 0; m < 4; ++m) {
#pragma unroll
      for (int kk = 0; kk < 2; ++kk) {
        int c16 = kk * 4 + khalf;
        int rowa = wr * 64 + m * 16 + r16;
        int rowb = wc * 64 + m * 16 + r16;
        af[m][kk] = *(const bf16x8*)(As + rowa * 64 + ((c16 ^ (rowa & 7)) << 3));
        bf[m][kk] = *(const bf16x8*)(Bs + rowb * 64 + ((c16 ^ (rowb & 7)) << 3));
      }
    }
#pragma unroll
    for (int kk = 0; kk < 2; ++kk)
#pragma unroll
      for (int m = 0; m < 4; ++m)
#pragma unroll
        for (int nn = 0; nn < 4; ++nn)
          acc[m][nn] = __builtin_amdgcn_mfma_f32_16x16x32_bf16(
              af[m][kk], bf[nn][kk], acc[m][nn], 0, 0, 0);
    __syncthreads();
  }

  // epilogue: C/D layout col = lane&15, row = (lane>>4)*4 + reg
  const int rgrp = lane >> 4;
#pragma unroll
  for (int m = 0; m < 4; ++m)
#pragma unroll
    for (int nn = 0; nn < 4; ++nn) {
      int col = bn + wc * 64 + nn * 16 + r16;
#pragma unroll
      for (int rg = 0; rg < 4; ++rg) {
        int row = bm + wr * 64 + m * 16 + rgrp * 4 + rg;
        float v = acc[m][nn][rg];
        if (MODE == 2) v += res[(size_t)row * ldres + col];
        C[(size_t)row * ldc + col] = v;
      }
    }
}

// ---------------- fp32 tiled NT GEMM (small GEMMs: x_proj, dt_proj) ----------------
// mode 0: store acc ; mode 1: store softplus(acc + bias[n])
#define BM 64
#define BN 64
#define BK 32
#define PADR 68

__global__ __launch_bounds__(256) void gemm_nt(
    const float* __restrict__ A, int lda,
    const float* __restrict__ Bw, int ldb,
    float* __restrict__ C, int ldc,
    int Mrows, int Ncols, int Kdim,
    int mode, const float* __restrict__ bias)
{
  __shared__ float as[BK][PADR];
  __shared__ float bs[BK][PADR];
  int bm = blockIdx.y * BM;
  int bn = blockIdx.x * BN;
  int t  = threadIdx.x;
  int tx = t & 15, ty = t >> 4;

  float acc[4][4] = {};

  int m0 = t >> 3;
  int kq = t & 7;
  const float4 z4 = {0.f, 0.f, 0.f, 0.f};

  for (int k0 = 0; k0 < Kdim; k0 += BK) {
    float4 a0 = *(const float4*)(A + (size_t)(bm + m0) * lda + k0 + kq * 4);
    float4 a1 = *(const float4*)(A + (size_t)(bm + m0 + 32) * lda + k0 + kq * 4);
    float4 b0 = (bn + m0 < Ncols)
        ? *(const float4*)(Bw + (size_t)(bn + m0) * ldb + k0 + kq * 4) : z4;
    float4 b1 = (bn + m0 + 32 < Ncols)
        ? *(const float4*)(Bw + (size_t)(bn + m0 + 32) * ldb + k0 + kq * 4) : z4;
    as[kq * 4 + 0][m0] = a0.x;  as[kq * 4 + 1][m0] = a0.y;
    as[kq * 4 + 2][m0] = a0.z;  as[kq * 4 + 3][m0] = a0.w;
    as[kq * 4 + 0][m0 + 32] = a1.x;  as[kq * 4 + 1][m0 + 32] = a1.y;
    as[kq * 4 + 2][m0 + 32] = a1.z;  as[kq * 4 + 3][m0 + 32] = a1.w;
    bs[kq * 4 + 0][m0] = b0.x;  bs[kq * 4 + 1][m0] = b0.y;
    bs[kq * 4 + 2][m0] = b0.z;  bs[kq * 4 + 3][m0] = b0.w;
    bs[kq * 4 + 0][m0 + 32] = b1.x;  bs[kq * 4 + 1][m0 + 32] = b1.y;
    bs[kq * 4 + 2][m0 + 32] = b1.z;  bs[kq * 4 + 3][m0 + 32] = b1.w;
    __syncthreads();

#pragma unroll
    for (int kk = 0; kk < BK; ++kk) {
      float4 a4 = *(const float4*)&as[kk][ty * 4];
      float4 b4 = *(const float4*)&bs[kk][tx * 4];
      float ar[4] = {a4.x, a4.y, a4.z, a4.w};
      float br[4] = {b4.x, b4.y, b4.z, b4.w};
#pragma unroll
      for (int i = 0; i < 4; ++i)
#pragma unroll
        for (int j = 0; j < 4; ++j)
          acc[i][j] = fmaf(ar[i], br[j], acc[i][j]);
    }
    __syncthreads();
  }

#pragma unroll
  for (int i = 0; i < 4; ++i) {
    int r = bm + ty * 4 + i;
    int c = bn + tx * 4;
    float vv[4];
#pragma unroll
    for (int j = 0; j < 4; ++j) {
      float v = acc[i][j];
      if (mode == 1) {
        v += bias[c + j];
        v = (v > 20.f) ? v : log1pf(expf(v));
      }
      vv[j] = v;
    }
    float4 o = {vv[0], vv[1], vv[2], vv[3]};
    *(float4*)(C + (size_t)r * ldc + c) = o;
  }
}

// ---------------- depthwise causal conv (K=4) + SiLU ----------------
#define LCH 128
__global__ __launch_bounds__(256) void conv_silu_kernel(
    const float* __restrict__ xz, const float* __restrict__ cw,
    const float* __restrict__ cb, float* __restrict__ u)
{
  int d  = blockIdx.x * 256 + threadIdx.x;
  int l0 = blockIdx.y * LCH;
  int b  = blockIdx.z;
  float w0 = cw[d * 4 + 0], w1 = cw[d * 4 + 1];
  float w2 = cw[d * 4 + 2], w3 = cw[d * 4 + 3];
  float bias = cb[d];
  const float* xi = xz + (size_t)(b * L_) * XZW_ + d;
  float x3 = (l0 >= 3) ? xi[(size_t)(l0 - 3) * XZW_] : 0.f;
  float x2 = (l0 >= 2) ? xi[(size_t)(l0 - 2) * XZW_] : 0.f;
  float x1 = (l0 >= 1) ? xi[(size_t)(l0 - 1) * XZW_] : 0.f;
  for (int l = l0; l < l0 + LCH; ++l) {
    float x0 = xi[(size_t)l * XZW_];
    float v = w0 * x3 + w1 * x2 + w2 * x1 + w3 * x0 + bias;
    float uu = v / (1.f + __expf(-v));
    u[((size_t)(b * L_) + l) * DI_ + d] = uu;
    x3 = x2; x2 = x1; x1 = x0;
  }
}

// ---------------- chunked selective scan ----------------
// pass1: per-chunk (prod dA, h_end) with h0=0
__global__ __launch_bounds__(256) void scan_p1(
    const float* __restrict__ dlt, const float* __restrict__ u,
    const float* __restrict__ xdbl, const float* __restrict__ A_log,
    float* __restrict__ Pbuf, float* __restrict__ hend)
{
  int t = threadIdx.x;
  int n = t & 15, cl = t >> 4;
  int d = blockIdx.x * 16 + cl;
  int b = blockIdx.y;
  int c = blockIdx.z;
  int l0 = c * CLEN_;
  float Adn = -__expf(A_log[d * NS_ + n]);
  float h = 0.f, P = 1.f;
  const float* dp = dlt + ((size_t)(b * L_) + l0) * DI_ + d;
  const float* up = u   + ((size_t)(b * L_) + l0) * DI_ + d;
  const float* xp = xdbl + ((size_t)(b * L_) + l0) * XDW_ + DTR_ + n;
  for (int l = 0; l < CLEN_; ++l) {
    float dv = dp[(size_t)l * DI_];
    float uv = up[(size_t)l * DI_];
    float Bv = xp[l * XDW_];
    float dA = __expf(dv * Adn);
    h = dA * h + dv * Bv * uv;
    P *= dA;
  }
  size_t i = ((size_t)(b * CH_ + c) * DI_ + d) * NS_ + n;
  Pbuf[i] = P;
  hend[i] = h;
}

// pass2: propagate chunk-boundary states. hin written in-place into Pbuf.
__global__ __launch_bounds__(256) void scan_p2(
    float* __restrict__ Pbuf, const float* __restrict__ hend)
{
  int tid = blockIdx.x * 256 + threadIdx.x;   // over B*DI*NS = 65536
  int n = tid & 15;
  int d = (tid >> 4) & (DI_ - 1);
  int b = tid >> 15;
  float h = 0.f;
  for (int c = 0; c < CH_; ++c) {
    size_t i = ((size_t)(b * CH_ + c) * DI_ + d) * NS_ + n;
    float Pv = Pbuf[i];
    float he = hend[i];
    Pbuf[i] = h;                 // h_in for chunk c
    h = Pv * h + he;
  }
}

// pass3: exact recurrence from true h_in; fused (y + u*D)*silu(z) -> bf16
__global__ __launch_bounds__(256) void scan_p3(
    const float* __restrict__ dlt, const float* __restrict__ u,
    const float* __restrict__ xdbl, const float* __restrict__ A_log,
    const float* __restrict__ hin, const float* __restrict__ xz,
    const float* __restrict__ Dp, unsigned short* __restrict__ yb)
{
  int t = threadIdx.x;
  int n = t & 15, cl = t >> 4;
  int d = blockIdx.x * 16 + cl;
  int b = blockIdx.y;
  int c = blockIdx.z;
  int l0 = c * CLEN_;
  float Adn = -__expf(A_log[d * NS_ + n]);
  size_t i0 = ((size_t)(b * CH_ + c) * DI_ + d) * NS_ + n;
  float h = hin[i0];
  float Dd = Dp[d];
  const float* dp = dlt + ((size_t)(b * L_) + l0) * DI_ + d;
  const float* up = u   + ((size_t)(b * L_) + l0) * DI_ + d;
  const float* xp = xdbl + ((size_t)(b * L_) + l0) * XDW_ + DTR_ + n;
  const float* zp = xz + ((size_t)(b * L_) + l0) * XZW_ + DI_ + d;
  unsigned short* yp = yb + ((size_t)(b * L_) + l0) * DI_ + d;
  for (int l = 0; l < CLEN_; ++l) {
    float dv = dp[(size_t)l * DI_];
    float uv = up[(size_t)l * DI_];
    float Bv = xp[l * XDW_];
    float Cv = xp[l * XDW_ + NS_];
    float dA = __expf(dv * Adn);
    h = dA * h + dv * Bv * uv;
    float py = h * Cv;
    py += __shfl_xor(py, 1);
    py += __shfl_xor(py, 2);
    py += __shfl_xor(py, 4);
    py += __shfl_xor(py, 8);
    if (n == 0) {
      float z = zp[(size_t)l * XZW_];
      float zs = z / (1.f + __expf(-z));
      yp[(size_t)l * DI_] = f2bf((py + uv * Dd) * zs);
    }
  }
}

extern "C" void kernel_launch(void* const* d_in, const int* in_sizes, int n_in,
                              void* d_out, int out_size, void* d_ws, size_t ws_size,
                              hipStream_t stream)
{
  const float* x         = (const float*)d_in[0];
  const float* ln_g      = (const float*)d_in[1];
  const float* ln_b      = (const float*)d_in[2];
  const float* in_proj_w = (const float*)d_in[3];
  const float* conv_w    = (const float*)d_in[4];
  const float* conv_b    = (const float*)d_in[5];
  const float* x_proj_w  = (const float*)d_in[6];
  const float* dt_proj_w = (const float*)d_in[7];
  const float* dt_proj_b = (const float*)d_in[8];
  const float* A_log     = (const float*)d_in[9];
  const float* Dp        = (const float*)d_in[10];
  const float* out_proj_w= (const float*)d_in[11];
  float* out = (float*)d_out;

  float* ws = (float*)d_ws;
  float* xz   = ws;                  // 2048*4096          = 8,388,608 f
  float* u    = ws + 8388608;        // 2048*2048          = 4,194,304 f
  float* xdbl = ws + 12582912;       // 2048*128           =   262,144 f
  float* dlt  = ws + 12845056;       // 2048*2048          = 4,194,304 f
  unsigned short* xnb   = (unsigned short*)(ws + 17039360); // 2048*1024 bf16 (1,048,576 f)
  unsigned short* winb  = (unsigned short*)(ws + 18087936); // 4096*1024 bf16 (2,097,152 f)
  unsigned short* woutb = (unsigned short*)(ws + 20185088); // 1024*2048 bf16 (1,048,576 f)
  unsigned short* yb    = (unsigned short*)(ws + 21233664); // 2048*2048 bf16 (1,048,576 f)
  float* Pbuf = ws + 22282240;       // 2*8*2048*16        =   524,288 f
  float* hend = ws + 22806528;       // 2*8*2048*16        =   524,288 f
  // total 23,330,816 floats = 93.3 MB

  // 1. LayerNorm -> bf16
  ln_kernel<<<M_, 256, 0, stream>>>(x, ln_g, ln_b, xnb);

  // 2. weight conversions fp32 -> bf16
  f2bf_kernel<<<4096, 256, 0, stream>>>((const float4*)in_proj_w, (u16x4*)winb);
  f2bf_kernel<<<2048, 256, 0, stream>>>((const float4*)out_proj_w, (u16x4*)woutb);

  // 3. in_proj (MFMA): xz = xn @ in_proj_w^T  (2048x1024 * 4096x1024^T)
  gemm_mfma<0><<<dim3(XZW_ / 128, M_ / 128), 256, 0, stream>>>(
      (const short*)xnb, DM_, (const short*)winb, DM_, xz, XZW_, DM_, nullptr, 0);

  // 4. conv + silu -> u
  conv_silu_kernel<<<dim3(DI_ / 256, L_ / LCH, B_), 256, 0, stream>>>(
      xz, conv_w, conv_b, u);

  // 5. x_proj: xdbl = u @ x_proj_w^T  (N=96, guarded; stored into 128-wide buf)
  gemm_nt<<<dim3(XDW_ / BN, M_ / BM), 256, 0, stream>>>(
      u, DI_, x_proj_w, DI_, xdbl, XDW_, M_, 96, DI_, 0, nullptr);

  // 6. dt_proj + softplus: dlt = softplus(xdbl[:, :64] @ dt_proj_w^T + b)
  gemm_nt<<<dim3(DI_ / BN, M_ / BM), 256, 0, stream>>>(
      xdbl, XDW_, dt_proj_w, DTR_, dlt, DI_, M_, DI_, DTR_, 1, dt_proj_b);

  // 7. chunked scan
  scan_p1<<<dim3(DI_ / 16, B_, CH_), 256, 0, stream>>>(dlt, u, xdbl, A_log, Pbuf, hend);
  scan_p2<<<(B_ * DI_ * NS_) / 256, 256, 0, stream>>>(Pbuf, hend);
  scan_p3<<<dim3(DI_ / 16, B_, CH_), 256, 0, stream>>>(
      dlt, u, xdbl, A_log, Pbuf, xz, Dp, yb);

  // 8. out_proj (MFMA) + residual: out = x + y @ out_proj_w^T
  gemm_mfma<2><<<dim3(DM_ / 128, M_ / 128), 256, 0, stream>>>(
      (const short*)yb, DI_, (const short*)woutb, DI_, out, DM_, DI_, x, DM_);
}

// Round 7
// 365.238 us; speedup vs baseline: 3.0318x; 1.3361x over previous
//
#include <hip/hip_runtime.h>
#include <hip/hip_bf16.h>
#include <math.h>

#define B_   2
#define L_   1024
#define DM_  1024
#define DI_  2048
#define NS_  16
#define DTR_ 64
#define M_   (B_ * L_)          // 2048 rows
#define XZW_ (2 * DI_)          // 4096
#define XDW_ 128                // padded x_proj output width (dt|B|C|pad)
#define CH_  8                  // scan chunks
#define CLEN_ (L_ / CH_)        // 128
#define SK_  8                  // x_proj split-K chunks
#define KCH_ (DI_ / SK_)        // 256

typedef __attribute__((ext_vector_type(8))) short bf16x8;
typedef __attribute__((ext_vector_type(4))) float f32x4;
typedef __attribute__((ext_vector_type(4))) unsigned short u16x4;

static __device__ __forceinline__ unsigned short f2bf(float f) {
  __hip_bfloat16 h = __float2bfloat16(f);
  return *reinterpret_cast<unsigned short*>(&h);
}

// ---------------- LayerNorm -> bf16 ----------------
__global__ __launch_bounds__(256) void ln_kernel(
    const float* __restrict__ x, const float* __restrict__ g,
    const float* __restrict__ b, unsigned short* __restrict__ xnb)
{
  int r = blockIdx.x;
  int t = threadIdx.x;
  const float4* xr = (const float4*)(x + (size_t)r * DM_);
  float4 v = xr[t];
  float s  = v.x + v.y + v.z + v.w;
  float ss = v.x * v.x + v.y * v.y + v.z * v.z + v.w * v.w;
  for (int m = 32; m >= 1; m >>= 1) {
    s  += __shfl_down(s, m);
    ss += __shfl_down(ss, m);
  }
  __shared__ float sb[4], ssb[4];
  int w = t >> 6, lane = t & 63;
  if (lane == 0) { sb[w] = s; ssb[w] = ss; }
  __syncthreads();
  s  = sb[0] + sb[1] + sb[2] + sb[3];
  ss = ssb[0] + ssb[1] + ssb[2] + ssb[3];
  float mu  = s * (1.f / DM_);
  float var = ss * (1.f / DM_) - mu * mu;
  float rs  = rsqrtf(var + 1e-5f);
  float4 gv = ((const float4*)g)[t];
  float4 bv = ((const float4*)b)[t];
  u16x4 o;
  o[0] = f2bf((v.x - mu) * rs * gv.x + bv.x);
  o[1] = f2bf((v.y - mu) * rs * gv.y + bv.y);
  o[2] = f2bf((v.z - mu) * rs * gv.z + bv.z);
  o[3] = f2bf((v.w - mu) * rs * gv.w + bv.w);
  ((u16x4*)xnb)[r * 256 + t] = o;
}

// ---------------- fp32 -> bf16 bulk convert ----------------
__global__ __launch_bounds__(256) void f2bf_kernel(
    const float4* __restrict__ in, u16x4* __restrict__ outp)
{
  int i = blockIdx.x * 256 + threadIdx.x;
  float4 v = in[i];
  u16x4 o;
  o[0] = f2bf(v.x); o[1] = f2bf(v.y); o[2] = f2bf(v.z); o[3] = f2bf(v.w);
  outp[i] = o;
}

// ---------------- bf16 MFMA GEMM NT: C[m,n] = sum_k A[m,k]*Bw[n,k] ----------------
// 128x128 tile, BK=64, 4 waves. LDS XOR-swizzled via pre-swizzled global source
// (linear global_load_lds dest). MODE 0: store ; MODE 2: store + res.
template<int MODE>
__global__ __launch_bounds__(256) void gemm_mfma(
    const short* __restrict__ A, int lda,
    const short* __restrict__ Bw, int ldb,
    float* __restrict__ C, int ldc, int Kdim,
    const float* __restrict__ res, int ldres)
{
  __shared__ __align__(16) short As[128 * 64];
  __shared__ __align__(16) short Bs[128 * 64];
  const int bm = blockIdx.y * 128, bn = blockIdx.x * 128;
  const int t = threadIdx.x, wid = t >> 6, lane = t & 63;
  const int wr = wid >> 1, wc = wid & 1;

  f32x4 acc[4][4];
#pragma unroll
  for (int i = 0; i < 4; ++i)
#pragma unroll
    for (int j = 0; j < 4; ++j) acc[i][j] = (f32x4){0.f, 0.f, 0.f, 0.f};

  const int srow = wid * 8 + (lane >> 3);
  const int sc   = lane & 7;
  const int r16 = lane & 15, khalf = lane >> 4;

  for (int k0 = 0; k0 < Kdim; k0 += 64) {
#pragma unroll
    for (int q = 0; q < 4; ++q) {
      int row = q * 32 + srow;
      int csw = sc ^ (row & 7);
      const short* gA = A + (size_t)(bm + row) * lda + k0 + csw * 8;
      const short* gB = Bw + (size_t)(bn + row) * ldb + k0 + csw * 8;
      __builtin_amdgcn_global_load_lds(
          (const __attribute__((address_space(1))) void*)gA,
          (__attribute__((address_space(3))) void*)(As + q * 2048 + wid * 512),
          16, 0, 0);
      __builtin_amdgcn_global_load_lds(
          (const __attribute__((address_space(1))) void*)gB,
          (__attribute__((address_space(3))) void*)(Bs + q * 2048 + wid * 512),
          16, 0, 0);
    }
    __syncthreads();

    bf16x8 af[4][2], bf[4][2];
#pragma unroll
    for (int m = 0; m < 4; ++m) {
#pragma unroll
      for (int kk = 0; kk < 2; ++kk) {
        int c16 = kk * 4 + khalf;
        int rowa = wr * 64 + m * 16 + r16;
        int rowb = wc * 64 + m * 16 + r16;
        af[m][kk] = *(const bf16x8*)(As + rowa * 64 + ((c16 ^ (rowa & 7)) << 3));
        bf[m][kk] = *(const bf16x8*)(Bs + rowb * 64 + ((c16 ^ (rowb & 7)) << 3));
      }
    }
#pragma unroll
    for (int kk = 0; kk < 2; ++kk)
#pragma unroll
      for (int m = 0; m < 4; ++m)
#pragma unroll
        for (int nn = 0; nn < 4; ++nn)
          acc[m][nn] = __builtin_amdgcn_mfma_f32_16x16x32_bf16(
              af[m][kk], bf[nn][kk], acc[m][nn], 0, 0, 0);
    __syncthreads();
  }

  const int rgrp = lane >> 4;
#pragma unroll
  for (int m = 0; m < 4; ++m)
#pragma unroll
    for (int nn = 0; nn < 4; ++nn) {
      int col = bn + wc * 64 + nn * 16 + r16;
#pragma unroll
      for (int rg = 0; rg < 4; ++rg) {
        int row = bm + wr * 64 + m * 16 + rgrp * 4 + rg;
        float v = acc[m][nn][rg];
        if (MODE == 2) v += res[(size_t)row * ldres + col];
        C[(size_t)row * ldc + col] = v;
      }
    }
}

// ---------------- fp32 tiled NT GEMM ----------------
// mode 0: store acc ; mode 1: store softplus(acc + bias[n])
#define BM 64
#define BN 64
#define BK 32
#define PADR 68

__global__ __launch_bounds__(256) void gemm_nt(
    const float* __restrict__ A, int lda,
    const float* __restrict__ Bw, int ldb,
    float* __restrict__ C, int ldc,
    int Mrows, int Ncols, int Kdim,
    int mode, const float* __restrict__ bias)
{
  __shared__ float as[BK][PADR];
  __shared__ float bs[BK][PADR];
  int bm = blockIdx.y * BM;
  int bn = blockIdx.x * BN;
  int t  = threadIdx.x;
  int tx = t & 15, ty = t >> 4;

  float acc[4][4] = {};

  int m0 = t >> 3;
  int kq = t & 7;
  const float4 z4 = {0.f, 0.f, 0.f, 0.f};

  for (int k0 = 0; k0 < Kdim; k0 += BK) {
    float4 a0 = *(const float4*)(A + (size_t)(bm + m0) * lda + k0 + kq * 4);
    float4 a1 = *(const float4*)(A + (size_t)(bm + m0 + 32) * lda + k0 + kq * 4);
    float4 b0 = (bn + m0 < Ncols)
        ? *(const float4*)(Bw + (size_t)(bn + m0) * ldb + k0 + kq * 4) : z4;
    float4 b1 = (bn + m0 + 32 < Ncols)
        ? *(const float4*)(Bw + (size_t)(bn + m0 + 32) * ldb + k0 + kq * 4) : z4;
    as[kq * 4 + 0][m0] = a0.x;  as[kq * 4 + 1][m0] = a0.y;
    as[kq * 4 + 2][m0] = a0.z;  as[kq * 4 + 3][m0] = a0.w;
    as[kq * 4 + 0][m0 + 32] = a1.x;  as[kq * 4 + 1][m0 + 32] = a1.y;
    as[kq * 4 + 2][m0 + 32] = a1.z;  as[kq * 4 + 3][m0 + 32] = a1.w;
    bs[kq * 4 + 0][m0] = b0.x;  bs[kq * 4 + 1][m0] = b0.y;
    bs[kq * 4 + 2][m0] = b0.z;  bs[kq * 4 + 3][m0] = b0.w;
    bs[kq * 4 + 0][m0 + 32] = b1.x;  bs[kq * 4 + 1][m0 + 32] = b1.y;
    bs[kq * 4 + 2][m0 + 32] = b1.z;  bs[kq * 4 + 3][m0 + 32] = b1.w;
    __syncthreads();

#pragma unroll
    for (int kk = 0; kk < BK; ++kk) {
      float4 a4 = *(const float4*)&as[kk][ty * 4];
      float4 b4 = *(const float4*)&bs[kk][tx * 4];
      float ar[4] = {a4.x, a4.y, a4.z, a4.w};
      float br[4] = {b4.x, b4.y, b4.z, b4.w};
#pragma unroll
      for (int i = 0; i < 4; ++i)
#pragma unroll
        for (int j = 0; j < 4; ++j)
          acc[i][j] = fmaf(ar[i], br[j], acc[i][j]);
    }
    __syncthreads();
  }

#pragma unroll
  for (int i = 0; i < 4; ++i) {
    int r = bm + ty * 4 + i;
    int c = bn + tx * 4;
    float vv[4];
#pragma unroll
    for (int j = 0; j < 4; ++j) {
      float v = acc[i][j];
      if (mode == 1) {
        v += bias[c + j];
        v = (v > 20.f) ? v : log1pf(expf(v));
      }
      vv[j] = v;
    }
    float4 o = {vv[0], vv[1], vv[2], vv[3]};
    *(float4*)(C + (size_t)r * ldc + c) = o;
  }
}

// ---------------- split-K fp32 NT GEMM for x_proj ----------------
// grid (XDW_/BN=2, M_/BM=32, SK_=8); writes partials part[sk][m][128]
__global__ __launch_bounds__(256) void gemm_nt_sk(
    const float* __restrict__ A, int lda,
    const float* __restrict__ Bw, int ldb,
    float* __restrict__ part, int Ncols)
{
  __shared__ float as[BK][PADR];
  __shared__ float bs[BK][PADR];
  int bm = blockIdx.y * BM;
  int bn = blockIdx.x * BN;
  int sk = blockIdx.z;
  int t  = threadIdx.x;
  int tx = t & 15, ty = t >> 4;

  float acc[4][4] = {};

  int m0 = t >> 3;
  int kq = t & 7;
  const float4 z4 = {0.f, 0.f, 0.f, 0.f};

  for (int k0 = sk * KCH_; k0 < (sk + 1) * KCH_; k0 += BK) {
    float4 a0 = *(const float4*)(A + (size_t)(bm + m0) * lda + k0 + kq * 4);
    float4 a1 = *(const float4*)(A + (size_t)(bm + m0 + 32) * lda + k0 + kq * 4);
    float4 b0 = (bn + m0 < Ncols)
        ? *(const float4*)(Bw + (size_t)(bn + m0) * ldb + k0 + kq * 4) : z4;
    float4 b1 = (bn + m0 + 32 < Ncols)
        ? *(const float4*)(Bw + (size_t)(bn + m0 + 32) * ldb + k0 + kq * 4) : z4;
    as[kq * 4 + 0][m0] = a0.x;  as[kq * 4 + 1][m0] = a0.y;
    as[kq * 4 + 2][m0] = a0.z;  as[kq * 4 + 3][m0] = a0.w;
    as[kq * 4 + 0][m0 + 32] = a1.x;  as[kq * 4 + 1][m0 + 32] = a1.y;
    as[kq * 4 + 2][m0 + 32] = a1.z;  as[kq * 4 + 3][m0 + 32] = a1.w;
    bs[kq * 4 + 0][m0] = b0.x;  bs[kq * 4 + 1][m0] = b0.y;
    bs[kq * 4 + 2][m0] = b0.z;  bs[kq * 4 + 3][m0] = b0.w;
    bs[kq * 4 + 0][m0 + 32] = b1.x;  bs[kq * 4 + 1][m0 + 32] = b1.y;
    bs[kq * 4 + 2][m0 + 32] = b1.z;  bs[kq * 4 + 3][m0 + 32] = b1.w;
    __syncthreads();

#pragma unroll
    for (int kk = 0; kk < BK; ++kk) {
      float4 a4 = *(const float4*)&as[kk][ty * 4];
      float4 b4 = *(const float4*)&bs[kk][tx * 4];
      float ar[4] = {a4.x, a4.y, a4.z, a4.w};
      float br[4] = {b4.x, b4.y, b4.z, b4.w};
#pragma unroll
      for (int i = 0; i < 4; ++i)
#pragma unroll
        for (int j = 0; j < 4; ++j)
          acc[i][j] = fmaf(ar[i], br[j], acc[i][j]);
    }
    __syncthreads();
  }

  float* outp = part + (size_t)sk * M_ * XDW_;
#pragma unroll
  for (int i = 0; i < 4; ++i) {
    int r = bm + ty * 4 + i;
    int c = bn + tx * 4;
    float4 o = {acc[i][0], acc[i][1], acc[i][2], acc[i][3]};
    *(float4*)(outp + (size_t)r * XDW_ + c) = o;
  }
}

// reduce partials: xdbl[i] = sum_sk part[sk][i]
__global__ __launch_bounds__(256) void reduce_sk(
    const float* __restrict__ part, float* __restrict__ xdbl)
{
  int i = blockIdx.x * 256 + threadIdx.x;   // over M_*XDW_
  float s = 0.f;
#pragma unroll
  for (int sk = 0; sk < SK_; ++sk) s += part[(size_t)sk * M_ * XDW_ + i];
  xdbl[i] = s;
}

// ---------------- depthwise causal conv (K=4) + SiLU ----------------
#define LCH 32
__global__ __launch_bounds__(256) void conv_silu_kernel(
    const float* __restrict__ xz, const float* __restrict__ cw,
    const float* __restrict__ cb, float* __restrict__ u)
{
  int d  = blockIdx.x * 256 + threadIdx.x;
  int l0 = blockIdx.y * LCH;
  int b  = blockIdx.z;
  float w0 = cw[d * 4 + 0], w1 = cw[d * 4 + 1];
  float w2 = cw[d * 4 + 2], w3 = cw[d * 4 + 3];
  float bias = cb[d];
  const float* xi = xz + (size_t)(b * L_) * XZW_ + d;
  float x3 = (l0 >= 3) ? xi[(size_t)(l0 - 3) * XZW_] : 0.f;
  float x2 = (l0 >= 2) ? xi[(size_t)(l0 - 2) * XZW_] : 0.f;
  float x1 = (l0 >= 1) ? xi[(size_t)(l0 - 1) * XZW_] : 0.f;
  for (int l = l0; l < l0 + LCH; ++l) {
    float x0 = xi[(size_t)l * XZW_];
    float v = w0 * x3 + w1 * x2 + w2 * x1 + w3 * x0 + bias;
    float uu = v / (1.f + __expf(-v));
    u[((size_t)(b * L_) + l) * DI_ + d] = uu;
    x3 = x2; x2 = x1; x1 = x0;
  }
}

// ---------------- chunked selective scan ----------------
__global__ __launch_bounds__(256) void scan_p1(
    const float* __restrict__ dlt, const float* __restrict__ u,
    const float* __restrict__ xdbl, const float* __restrict__ A_log,
    float* __restrict__ Pbuf, float* __restrict__ hend)
{
  int t = threadIdx.x;
  int n = t & 15, cl = t >> 4;
  int d = blockIdx.x * 16 + cl;
  int b = blockIdx.y;
  int c = blockIdx.z;
  int l0 = c * CLEN_;
  float Adn = -__expf(A_log[d * NS_ + n]);
  float h = 0.f, S = 0.f;
  const float* dp = dlt + ((size_t)(b * L_) + l0) * DI_ + d;
  const float* up = u   + ((size_t)(b * L_) + l0) * DI_ + d;
  const float* xp = xdbl + ((size_t)(b * L_) + l0) * XDW_ + DTR_ + n;
  for (int l = 0; l < CLEN_; ++l) {
    float dv = dp[(size_t)l * DI_];
    float uv = up[(size_t)l * DI_];
    float Bv = xp[l * XDW_];
    float dA = __expf(dv * Adn);
    h = dA * h + dv * Bv * uv;
    S += dv;
  }
  size_t i = ((size_t)(b * CH_ + c) * DI_ + d) * NS_ + n;
  Pbuf[i] = __expf(S * Adn);   // prod of dA over chunk
  hend[i] = h;
}

__global__ __launch_bounds__(256) void scan_p2(
    float* __restrict__ Pbuf, const float* __restrict__ hend)
{
  int tid = blockIdx.x * 256 + threadIdx.x;
  int n = tid & 15;
  int d = (tid >> 4) & (DI_ - 1);
  int b = tid >> 15;
  float h = 0.f;
  for (int c = 0; c < CH_; ++c) {
    size_t i = ((size_t)(b * CH_ + c) * DI_ + d) * NS_ + n;
    float Pv = Pbuf[i];
    float he = hend[i];
    Pbuf[i] = h;
    h = Pv * h + he;
  }
}

__global__ __launch_bounds__(256) void scan_p3(
    const float* __restrict__ dlt, const float* __restrict__ u,
    const float* __restrict__ xdbl, const float* __restrict__ A_log,
    const float* __restrict__ hin, const float* __restrict__ xz,
    const float* __restrict__ Dp, unsigned short* __restrict__ yb)
{
  int t = threadIdx.x;
  int n = t & 15, cl = t >> 4;
  int d = blockIdx.x * 16 + cl;
  int b = blockIdx.y;
  int c = blockIdx.z;
  int l0 = c * CLEN_;
  float Adn = -__expf(A_log[d * NS_ + n]);
  size_t i0 = ((size_t)(b * CH_ + c) * DI_ + d) * NS_ + n;
  float h = hin[i0];
  float Dd = Dp[d];
  const float* dp = dlt + ((size_t)(b * L_) + l0) * DI_ + d;
  const float* up = u   + ((size_t)(b * L_) + l0) * DI_ + d;
  const float* xp = xdbl + ((size_t)(b * L_) + l0) * XDW_ + DTR_ + n;
  const float* zp = xz + ((size_t)(b * L_) + l0) * XZW_ + DI_ + d;
  unsigned short* yp = yb + ((size_t)(b * L_) + l0) * DI_ + d;
  for (int l = 0; l < CLEN_; ++l) {
    float dv = dp[(size_t)l * DI_];
    float uv = up[(size_t)l * DI_];
    float Bv = xp[l * XDW_];
    float Cv = xp[l * XDW_ + NS_];
    float dA = __expf(dv * Adn);
    h = dA * h + dv * Bv * uv;
    float py = h * Cv;
    py += __shfl_xor(py, 1);
    py += __shfl_xor(py, 2);
    py += __shfl_xor(py, 4);
    py += __shfl_xor(py, 8);
    if (n == 0) {
      float z = zp[(size_t)l * XZW_];
      float zs = z / (1.f + __expf(-z));
      yp[(size_t)l * DI_] = f2bf((py + uv * Dd) * zs);
    }
  }
}

extern "C" void kernel_launch(void* const* d_in, const int* in_sizes, int n_in,
                              void* d_out, int out_size, void* d_ws, size_t ws_size,
                              hipStream_t stream)
{
  const float* x         = (const float*)d_in[0];
  const float* ln_g      = (const float*)d_in[1];
  const float* ln_b      = (const float*)d_in[2];
  const float* in_proj_w = (const float*)d_in[3];
  const float* conv_w    = (const float*)d_in[4];
  const float* conv_b    = (const float*)d_in[5];
  const float* x_proj_w  = (const float*)d_in[6];
  const float* dt_proj_w = (const float*)d_in[7];
  const float* dt_proj_b = (const float*)d_in[8];
  const float* A_log     = (const float*)d_in[9];
  const float* Dp        = (const float*)d_in[10];
  const float* out_proj_w= (const float*)d_in[11];
  float* out = (float*)d_out;

  float* ws = (float*)d_ws;
  float* xz   = ws;                  // 2048*4096          = 8,388,608 f
  float* u    = ws + 8388608;        // 2048*2048          = 4,194,304 f
  float* xdbl = ws + 12582912;       // 2048*128           =   262,144 f
  float* dlt  = ws + 12845056;       // 2048*2048          = 4,194,304 f
  unsigned short* xnb   = (unsigned short*)(ws + 17039360); // 1,048,576 f
  float* winb_f = ws + 18087936;     // 4096*1024 bf16 OR sk-partials (2,097,152 f)
  unsigned short* winb  = (unsigned short*)winb_f;
  unsigned short* woutb = (unsigned short*)(ws + 20185088); // 1,048,576 f
  unsigned short* yb    = (unsigned short*)(ws + 21233664); // 1,048,576 f
  float* Pbuf = ws + 22282240;       // 524,288 f
  float* hend = ws + 22806528;       // 524,288 f
  // total 23,330,816 floats = 93.3 MB

  // 1. LayerNorm -> bf16
  ln_kernel<<<M_, 256, 0, stream>>>(x, ln_g, ln_b, xnb);

  // 2. weight conversions fp32 -> bf16
  f2bf_kernel<<<4096, 256, 0, stream>>>((const float4*)in_proj_w, (u16x4*)winb);
  f2bf_kernel<<<2048, 256, 0, stream>>>((const float4*)out_proj_w, (u16x4*)woutb);

  // 3. in_proj (MFMA): xz = xn @ in_proj_w^T
  gemm_mfma<0><<<dim3(XZW_ / 128, M_ / 128), 256, 0, stream>>>(
      (const short*)xnb, DM_, (const short*)winb, DM_, xz, XZW_, DM_, nullptr, 0);

  // 4. conv + silu -> u
  conv_silu_kernel<<<dim3(DI_ / 256, L_ / LCH, B_), 256, 0, stream>>>(
      xz, conv_w, conv_b, u);

  // 5. x_proj split-K (partials into winb region, dead after in_proj) + reduce
  gemm_nt_sk<<<dim3(XDW_ / BN, M_ / BM, SK_), 256, 0, stream>>>(
      u, DI_, x_proj_w, DI_, winb_f, 96);
  reduce_sk<<<(M_ * XDW_) / 256, 256, 0, stream>>>(winb_f, xdbl);

  // 6. dt_proj + softplus
  gemm_nt<<<dim3(DI_ / BN, M_ / BM), 256, 0, stream>>>(
      xdbl, XDW_, dt_proj_w, DTR_, dlt, DI_, M_, DI_, DTR_, 1, dt_proj_b);

  // 7. chunked scan
  scan_p1<<<dim3(DI_ / 16, B_, CH_), 256, 0, stream>>>(dlt, u, xdbl, A_log, Pbuf, hend);
  scan_p2<<<(B_ * DI_ * NS_) / 256, 256, 0, stream>>>(Pbuf, hend);
  scan_p3<<<dim3(DI_ / 16, B_, CH_), 256, 0, stream>>>(
      dlt, u, xdbl, A_log, Pbuf, xz, Dp, yb);

  // 8. out_proj (MFMA) + residual
  gemm_mfma<2><<<dim3(DM_ / 128, M_ / 128), 256, 0, stream>>>(
      (const short*)yb, DI_, (const short*)woutb, DI_, out, DM_, DI_, x, DM_);
}

// Round 8
// 302.996 us; speedup vs baseline: 3.6545x; 1.2054x over previous
//
#include <hip/hip_runtime.h>
#include <hip/hip_bf16.h>
#include <math.h>

#define B_   2
#define L_   1024
#define DM_  1024
#define DI_  2048
#define NS_  16
#define DTR_ 64
#define M_   (B_ * L_)          // 2048 rows
#define XZW_ (2 * DI_)          // 4096
#define XDW_ 128                // padded x_proj output width (dt|B|C|pad)
#define CH_  16                 // scan chunks
#define CLEN_ (L_ / CH_)        // 64
#define SK_  8                  // x_proj split-K chunks
#define KCH_ (DI_ / SK_)        // 256

typedef __attribute__((ext_vector_type(8))) short bf16x8;
typedef __attribute__((ext_vector_type(4))) float f32x4;
typedef __attribute__((ext_vector_type(4))) unsigned short u16x4;

static __device__ __forceinline__ unsigned short f2bf(float f) {
  __hip_bfloat16 h = __float2bfloat16(f);
  return *reinterpret_cast<unsigned short*>(&h);
}

// ---------------- LayerNorm -> bf16 ----------------
__global__ __launch_bounds__(256) void ln_kernel(
    const float* __restrict__ x, const float* __restrict__ g,
    const float* __restrict__ b, unsigned short* __restrict__ xnb)
{
  int r = blockIdx.x;
  int t = threadIdx.x;
  const float4* xr = (const float4*)(x + (size_t)r * DM_);
  float4 v = xr[t];
  float s  = v.x + v.y + v.z + v.w;
  float ss = v.x * v.x + v.y * v.y + v.z * v.z + v.w * v.w;
  for (int m = 32; m >= 1; m >>= 1) {
    s  += __shfl_down(s, m);
    ss += __shfl_down(ss, m);
  }
  __shared__ float sb[4], ssb[4];
  int w = t >> 6, lane = t & 63;
  if (lane == 0) { sb[w] = s; ssb[w] = ss; }
  __syncthreads();
  s  = sb[0] + sb[1] + sb[2] + sb[3];
  ss = ssb[0] + ssb[1] + ssb[2] + ssb[3];
  float mu  = s * (1.f / DM_);
  float var = ss * (1.f / DM_) - mu * mu;
  float rs  = rsqrtf(var + 1e-5f);
  float4 gv = ((const float4*)g)[t];
  float4 bv = ((const float4*)b)[t];
  u16x4 o;
  o[0] = f2bf((v.x - mu) * rs * gv.x + bv.x);
  o[1] = f2bf((v.y - mu) * rs * gv.y + bv.y);
  o[2] = f2bf((v.z - mu) * rs * gv.z + bv.z);
  o[3] = f2bf((v.w - mu) * rs * gv.w + bv.w);
  ((u16x4*)xnb)[r * 256 + t] = o;
}

// ---------------- fp32 -> bf16 bulk convert ----------------
__global__ __launch_bounds__(256) void f2bf_kernel(
    const float4* __restrict__ in, u16x4* __restrict__ outp)
{
  int i = blockIdx.x * 256 + threadIdx.x;
  float4 v = in[i];
  u16x4 o;
  o[0] = f2bf(v.x); o[1] = f2bf(v.y); o[2] = f2bf(v.z); o[3] = f2bf(v.w);
  outp[i] = o;
}

// ---------------- bf16 MFMA GEMM NT: C[m,n] = sum_k A[m,k]*Bw[n,k] ----------------
// 128x128 tile, BK=64, 4 waves. LDS XOR-swizzled via pre-swizzled global source
// (linear global_load_lds dest). MODE 0: store ; MODE 2: store + res.
template<int MODE>
__global__ __launch_bounds__(256) void gemm_mfma(
    const short* __restrict__ A, int lda,
    const short* __restrict__ Bw, int ldb,
    float* __restrict__ C, int ldc, int Kdim,
    const float* __restrict__ res, int ldres)
{
  __shared__ __align__(16) short As[128 * 64];
  __shared__ __align__(16) short Bs[128 * 64];
  const int bm = blockIdx.y * 128, bn = blockIdx.x * 128;
  const int t = threadIdx.x, wid = t >> 6, lane = t & 63;
  const int wr = wid >> 1, wc = wid & 1;

  f32x4 acc[4][4];
#pragma unroll
  for (int i = 0; i < 4; ++i)
#pragma unroll
    for (int j = 0; j < 4; ++j) acc[i][j] = (f32x4){0.f, 0.f, 0.f, 0.f};

  const int srow = wid * 8 + (lane >> 3);
  const int sc   = lane & 7;
  const int r16 = lane & 15, khalf = lane >> 4;

  for (int k0 = 0; k0 < Kdim; k0 += 64) {
#pragma unroll
    for (int q = 0; q < 4; ++q) {
      int row = q * 32 + srow;
      int csw = sc ^ (row & 7);
      const short* gA = A + (size_t)(bm + row) * lda + k0 + csw * 8;
      const short* gB = Bw + (size_t)(bn + row) * ldb + k0 + csw * 8;
      __builtin_amdgcn_global_load_lds(
          (const __attribute__((address_space(1))) void*)gA,
          (__attribute__((address_space(3))) void*)(As + q * 2048 + wid * 512),
          16, 0, 0);
      __builtin_amdgcn_global_load_lds(
          (const __attribute__((address_space(1))) void*)gB,
          (__attribute__((address_space(3))) void*)(Bs + q * 2048 + wid * 512),
          16, 0, 0);
    }
    __syncthreads();

    bf16x8 af[4][2], bf[4][2];
#pragma unroll
    for (int m = 0; m < 4; ++m) {
#pragma unroll
      for (int kk = 0; kk < 2; ++kk) {
        int c16 = kk * 4 + khalf;
        int rowa = wr * 64 + m * 16 + r16;
        int rowb = wc * 64 + m * 16 + r16;
        af[m][kk] = *(const bf16x8*)(As + rowa * 64 + ((c16 ^ (rowa & 7)) << 3));
        bf[m][kk] = *(const bf16x8*)(Bs + rowb * 64 + ((c16 ^ (rowb & 7)) << 3));
      }
    }
#pragma unroll
    for (int kk = 0; kk < 2; ++kk)
#pragma unroll
      for (int m = 0; m < 4; ++m)
#pragma unroll
        for (int nn = 0; nn < 4; ++nn)
          acc[m][nn] = __builtin_amdgcn_mfma_f32_16x16x32_bf16(
              af[m][kk], bf[nn][kk], acc[m][nn], 0, 0, 0);
    __syncthreads();
  }

  const int rgrp = lane >> 4;
#pragma unroll
  for (int m = 0; m < 4; ++m)
#pragma unroll
    for (int nn = 0; nn < 4; ++nn) {
      int col = bn + wc * 64 + nn * 16 + r16;
#pragma unroll
      for (int rg = 0; rg < 4; ++rg) {
        int row = bm + wr * 64 + m * 16 + rgrp * 4 + rg;
        float v = acc[m][nn][rg];
        if (MODE == 2) v += res[(size_t)row * ldres + col];
        C[(size_t)row * ldc + col] = v;
      }
    }
}

// ---------------- fp32 tiled NT GEMM ----------------
// mode 0: store acc ; mode 1: store softplus(acc + bias[n])
#define BM 64
#define BN 64
#define BK 32
#define PADR 68

__global__ __launch_bounds__(256) void gemm_nt(
    const float* __restrict__ A, int lda,
    const float* __restrict__ Bw, int ldb,
    float* __restrict__ C, int ldc,
    int Mrows, int Ncols, int Kdim,
    int mode, const float* __restrict__ bias)
{
  __shared__ float as[BK][PADR];
  __shared__ float bs[BK][PADR];
  int bm = blockIdx.y * BM;
  int bn = blockIdx.x * BN;
  int t  = threadIdx.x;
  int tx = t & 15, ty = t >> 4;

  float acc[4][4] = {};

  int m0 = t >> 3;
  int kq = t & 7;
  const float4 z4 = {0.f, 0.f, 0.f, 0.f};

  for (int k0 = 0; k0 < Kdim; k0 += BK) {
    float4 a0 = *(const float4*)(A + (size_t)(bm + m0) * lda + k0 + kq * 4);
    float4 a1 = *(const float4*)(A + (size_t)(bm + m0 + 32) * lda + k0 + kq * 4);
    float4 b0 = (bn + m0 < Ncols)
        ? *(const float4*)(Bw + (size_t)(bn + m0) * ldb + k0 + kq * 4) : z4;
    float4 b1 = (bn + m0 + 32 < Ncols)
        ? *(const float4*)(Bw + (size_t)(bn + m0 + 32) * ldb + k0 + kq * 4) : z4;
    as[kq * 4 + 0][m0] = a0.x;  as[kq * 4 + 1][m0] = a0.y;
    as[kq * 4 + 2][m0] = a0.z;  as[kq * 4 + 3][m0] = a0.w;
    as[kq * 4 + 0][m0 + 32] = a1.x;  as[kq * 4 + 1][m0 + 32] = a1.y;
    as[kq * 4 + 2][m0 + 32] = a1.z;  as[kq * 4 + 3][m0 + 32] = a1.w;
    bs[kq * 4 + 0][m0] = b0.x;  bs[kq * 4 + 1][m0] = b0.y;
    bs[kq * 4 + 2][m0] = b0.z;  bs[kq * 4 + 3][m0] = b0.w;
    bs[kq * 4 + 0][m0 + 32] = b1.x;  bs[kq * 4 + 1][m0 + 32] = b1.y;
    bs[kq * 4 + 2][m0 + 32] = b1.z;  bs[kq * 4 + 3][m0 + 32] = b1.w;
    __syncthreads();

#pragma unroll
    for (int kk = 0; kk < BK; ++kk) {
      float4 a4 = *(const float4*)&as[kk][ty * 4];
      float4 b4 = *(const float4*)&bs[kk][tx * 4];
      float ar[4] = {a4.x, a4.y, a4.z, a4.w};
      float br[4] = {b4.x, b4.y, b4.z, b4.w};
#pragma unroll
      for (int i = 0; i < 4; ++i)
#pragma unroll
        for (int j = 0; j < 4; ++j)
          acc[i][j] = fmaf(ar[i], br[j], acc[i][j]);
    }
    __syncthreads();
  }

#pragma unroll
  for (int i = 0; i < 4; ++i) {
    int r = bm + ty * 4 + i;
    int c = bn + tx * 4;
    float vv[4];
#pragma unroll
    for (int j = 0; j < 4; ++j) {
      float v = acc[i][j];
      if (mode == 1) {
        v += bias[c + j];
        v = (v > 20.f) ? v : log1pf(expf(v));
      }
      vv[j] = v;
    }
    float4 o = {vv[0], vv[1], vv[2], vv[3]};
    *(float4*)(C + (size_t)r * ldc + c) = o;
  }
}

// ---------------- split-K fp32 NT GEMM for x_proj ----------------
__global__ __launch_bounds__(256) void gemm_nt_sk(
    const float* __restrict__ A, int lda,
    const float* __restrict__ Bw, int ldb,
    float* __restrict__ part, int Ncols)
{
  __shared__ float as[BK][PADR];
  __shared__ float bs[BK][PADR];
  int bm = blockIdx.y * BM;
  int bn = blockIdx.x * BN;
  int sk = blockIdx.z;
  int t  = threadIdx.x;
  int tx = t & 15, ty = t >> 4;

  float acc[4][4] = {};

  int m0 = t >> 3;
  int kq = t & 7;
  const float4 z4 = {0.f, 0.f, 0.f, 0.f};

  for (int k0 = sk * KCH_; k0 < (sk + 1) * KCH_; k0 += BK) {
    float4 a0 = *(const float4*)(A + (size_t)(bm + m0) * lda + k0 + kq * 4);
    float4 a1 = *(const float4*)(A + (size_t)(bm + m0 + 32) * lda + k0 + kq * 4);
    float4 b0 = (bn + m0 < Ncols)
        ? *(const float4*)(Bw + (size_t)(bn + m0) * ldb + k0 + kq * 4) : z4;
    float4 b1 = (bn + m0 + 32 < Ncols)
        ? *(const float4*)(Bw + (size_t)(bn + m0 + 32) * ldb + k0 + kq * 4) : z4;
    as[kq * 4 + 0][m0] = a0.x;  as[kq * 4 + 1][m0] = a0.y;
    as[kq * 4 + 2][m0] = a0.z;  as[kq * 4 + 3][m0] = a0.w;
    as[kq * 4 + 0][m0 + 32] = a1.x;  as[kq * 4 + 1][m0 + 32] = a1.y;
    as[kq * 4 + 2][m0 + 32] = a1.z;  as[kq * 4 + 3][m0 + 32] = a1.w;
    bs[kq * 4 + 0][m0] = b0.x;  bs[kq * 4 + 1][m0] = b0.y;
    bs[kq * 4 + 2][m0] = b0.z;  bs[kq * 4 + 3][m0] = b0.w;
    bs[kq * 4 + 0][m0 + 32] = b1.x;  bs[kq * 4 + 1][m0 + 32] = b1.y;
    bs[kq * 4 + 2][m0 + 32] = b1.z;  bs[kq * 4 + 3][m0 + 32] = b1.w;
    __syncthreads();

#pragma unroll
    for (int kk = 0; kk < BK; ++kk) {
      float4 a4 = *(const float4*)&as[kk][ty * 4];
      float4 b4 = *(const float4*)&bs[kk][tx * 4];
      float ar[4] = {a4.x, a4.y, a4.z, a4.w};
      float br[4] = {b4.x, b4.y, b4.z, b4.w};
#pragma unroll
      for (int i = 0; i < 4; ++i)
#pragma unroll
        for (int j = 0; j < 4; ++j)
          acc[i][j] = fmaf(ar[i], br[j], acc[i][j]);
    }
    __syncthreads();
  }

  float* outp = part + (size_t)sk * M_ * XDW_;
#pragma unroll
  for (int i = 0; i < 4; ++i) {
    int r = bm + ty * 4 + i;
    int c = bn + tx * 4;
    float4 o = {acc[i][0], acc[i][1], acc[i][2], acc[i][3]};
    *(float4*)(outp + (size_t)r * XDW_ + c) = o;
  }
}

// reduce partials: xdbl[i] = sum_sk part[sk][i]
__global__ __launch_bounds__(256) void reduce_sk(
    const float* __restrict__ part, float* __restrict__ xdbl)
{
  int i = blockIdx.x * 256 + threadIdx.x;
  float s = 0.f;
#pragma unroll
  for (int sk = 0; sk < SK_; ++sk) s += part[(size_t)sk * M_ * XDW_ + i];
  xdbl[i] = s;
}

// ---------------- depthwise causal conv (K=4) + SiLU ----------------
#define LCH 32
__global__ __launch_bounds__(256) void conv_silu_kernel(
    const float* __restrict__ xz, const float* __restrict__ cw,
    const float* __restrict__ cb, float* __restrict__ u)
{
  int d  = blockIdx.x * 256 + threadIdx.x;
  int l0 = blockIdx.y * LCH;
  int b  = blockIdx.z;
  float w0 = cw[d * 4 + 0], w1 = cw[d * 4 + 1];
  float w2 = cw[d * 4 + 2], w3 = cw[d * 4 + 3];
  float bias = cb[d];
  const float* xi = xz + (size_t)(b * L_) * XZW_ + d;
  float x3 = (l0 >= 3) ? xi[(size_t)(l0 - 3) * XZW_] : 0.f;
  float x2 = (l0 >= 2) ? xi[(size_t)(l0 - 2) * XZW_] : 0.f;
  float x1 = (l0 >= 1) ? xi[(size_t)(l0 - 1) * XZW_] : 0.f;
  for (int l = l0; l < l0 + LCH; ++l) {
    float x0 = xi[(size_t)l * XZW_];
    float v = w0 * x3 + w1 * x2 + w2 * x1 + w3 * x0 + bias;
    float uu = v / (1.f + __expf(-v));
    u[((size_t)(b * L_) + l) * DI_ + d] = uu;
    x3 = x2; x2 = x1; x1 = x0;
  }
}

// ---------------- chunked selective scan (4 states/lane, 4 lanes/channel) ----
// thread t: ng = t&3 (n-group of 4), dl = t>>2 (0..63); d = bx*64+dl
// grid (DI/64, B, CH)
__global__ __launch_bounds__(256) void scan_p1(
    const float* __restrict__ dlt, const float* __restrict__ u,
    const float* __restrict__ xdbl, const float* __restrict__ A_log,
    float* __restrict__ Pbuf, float* __restrict__ hend)
{
  int t = threadIdx.x;
  int ng = t & 3, dl = t >> 2;
  int d = blockIdx.x * 64 + dl;
  int b = blockIdx.y;
  int c = blockIdx.z;
  int l0 = c * CLEN_;
  float4 Al = *(const float4*)(A_log + d * NS_ + ng * 4);
  float A0 = -__expf(Al.x), A1 = -__expf(Al.y), A2 = -__expf(Al.z), A3 = -__expf(Al.w);
  float h0 = 0.f, h1 = 0.f, h2 = 0.f, h3 = 0.f, S = 0.f;
  const float* dp = dlt + ((size_t)(b * L_) + l0) * DI_ + d;
  const float* up = u   + ((size_t)(b * L_) + l0) * DI_ + d;
  const float* xp = xdbl + ((size_t)(b * L_) + l0) * XDW_ + DTR_ + ng * 4;
  float dv = dp[0], uv = up[0];
  float4 Bv = *(const float4*)xp;
  for (int l = 0; l < CLEN_; ++l) {
    int ln = (l + 1 < CLEN_) ? l + 1 : l;
    float dv_n = dp[(size_t)ln * DI_];
    float uv_n = up[(size_t)ln * DI_];
    float4 Bv_n = *(const float4*)(xp + (size_t)ln * XDW_);
    float dvu = dv * uv;
    h0 = __expf(dv * A0) * h0 + dvu * Bv.x;
    h1 = __expf(dv * A1) * h1 + dvu * Bv.y;
    h2 = __expf(dv * A2) * h2 + dvu * Bv.z;
    h3 = __expf(dv * A3) * h3 + dvu * Bv.w;
    S += dv;
    dv = dv_n; uv = uv_n; Bv = Bv_n;
  }
  size_t i = ((size_t)((b * CH_ + c) * DI_) + d) * NS_ + ng * 4;
  float4 P; P.x = __expf(S * A0); P.y = __expf(S * A1);
  P.z = __expf(S * A2); P.w = __expf(S * A3);
  float4 H; H.x = h0; H.y = h1; H.z = h2; H.w = h3;
  *(float4*)(Pbuf + i) = P;
  *(float4*)(hend + i) = H;
}

__global__ __launch_bounds__(256) void scan_p2(
    float* __restrict__ Pbuf, const float* __restrict__ hend)
{
  int tid = blockIdx.x * 256 + threadIdx.x;   // over B*DI*NS = 65536
  int n = tid & 15;
  int d = (tid >> 4) & (DI_ - 1);
  int b = tid >> 15;
  float h = 0.f;
  for (int c = 0; c < CH_; ++c) {
    size_t i = ((size_t)((b * CH_ + c) * DI_) + d) * NS_ + n;
    float Pv = Pbuf[i];
    float he = hend[i];
    Pbuf[i] = h;
    h = Pv * h + he;
  }
}

__global__ __launch_bounds__(256) void scan_p3(
    const float* __restrict__ dlt, const float* __restrict__ u,
    const float* __restrict__ xdbl, const float* __restrict__ A_log,
    const float* __restrict__ hin, const float* __restrict__ xz,
    const float* __restrict__ Dp, unsigned short* __restrict__ yb)
{
  int t = threadIdx.x;
  int ng = t & 3, dl = t >> 2;
  int d = blockIdx.x * 64 + dl;
  int b = blockIdx.y;
  int c = blockIdx.z;
  int l0 = c * CLEN_;
  float4 Al = *(const float4*)(A_log + d * NS_ + ng * 4);
  float A0 = -__expf(Al.x), A1 = -__expf(Al.y), A2 = -__expf(Al.z), A3 = -__expf(Al.w);
  size_t i0 = ((size_t)((b * CH_ + c) * DI_) + d) * NS_ + ng * 4;
  float4 hv = *(const float4*)(hin + i0);
  float h0 = hv.x, h1 = hv.y, h2 = hv.z, h3 = hv.w;
  float Dd = Dp[d];
  const float* dp = dlt + ((size_t)(b * L_) + l0) * DI_ + d;
  const float* up = u   + ((size_t)(b * L_) + l0) * DI_ + d;
  const float* xp = xdbl + ((size_t)(b * L_) + l0) * XDW_ + DTR_ + ng * 4;
  const float* zp = xz + ((size_t)(b * L_) + l0) * XZW_ + DI_ + d;
  unsigned short* yp = yb + ((size_t)(b * L_) + l0) * DI_ + d;
  float dv = dp[0], uv = up[0];
  float4 Bv = *(const float4*)xp;
  float4 Cv = *(const float4*)(xp + NS_);
  for (int l = 0; l < CLEN_; ++l) {
    int ln = (l + 1 < CLEN_) ? l + 1 : l;
    float dv_n = dp[(size_t)ln * DI_];
    float uv_n = up[(size_t)ln * DI_];
    float4 Bv_n = *(const float4*)(xp + (size_t)ln * XDW_);
    float4 Cv_n = *(const float4*)(xp + (size_t)ln * XDW_ + NS_);
    float dvu = dv * uv;
    h0 = __expf(dv * A0) * h0 + dvu * Bv.x;
    h1 = __expf(dv * A1) * h1 + dvu * Bv.y;
    h2 = __expf(dv * A2) * h2 + dvu * Bv.z;
    h3 = __expf(dv * A3) * h3 + dvu * Bv.w;
    float py = h0 * Cv.x + h1 * Cv.y + h2 * Cv.z + h3 * Cv.w;
    py += __shfl_xor(py, 1);
    py += __shfl_xor(py, 2);
    if (ng == 0) {
      float z = zp[(size_t)l * XZW_];
      float zs = z / (1.f + __expf(-z));
      yp[(size_t)l * DI_] = f2bf((py + uv * Dd) * zs);
    }
    dv = dv_n; uv = uv_n; Bv = Bv_n; Cv = Cv_n;
  }
}

extern "C" void kernel_launch(void* const* d_in, const int* in_sizes, int n_in,
                              void* d_out, int out_size, void* d_ws, size_t ws_size,
                              hipStream_t stream)
{
  const float* x         = (const float*)d_in[0];
  const float* ln_g      = (const float*)d_in[1];
  const float* ln_b      = (const float*)d_in[2];
  const float* in_proj_w = (const float*)d_in[3];
  const float* conv_w    = (const float*)d_in[4];
  const float* conv_b    = (const float*)d_in[5];
  const float* x_proj_w  = (const float*)d_in[6];
  const float* dt_proj_w = (const float*)d_in[7];
  const float* dt_proj_b = (const float*)d_in[8];
  const float* A_log     = (const float*)d_in[9];
  const float* Dp        = (const float*)d_in[10];
  const float* out_proj_w= (const float*)d_in[11];
  float* out = (float*)d_out;

  float* ws = (float*)d_ws;
  float* xz   = ws;                  // 2048*4096          = 8,388,608 f
  float* u    = ws + 8388608;        // 2048*2048          = 4,194,304 f
  float* xdbl = ws + 12582912;       // 2048*128           =   262,144 f
  float* dlt  = ws + 12845056;       // 2048*2048          = 4,194,304 f
  unsigned short* xnb   = (unsigned short*)(ws + 17039360); // 1,048,576 f
  float* winb_f = ws + 18087936;     // 2,097,152 f: winb bf16 / sk-partials / Pbuf+hend
  unsigned short* winb  = (unsigned short*)winb_f;
  unsigned short* woutb = (unsigned short*)(ws + 20185088); // 1,048,576 f
  unsigned short* yb    = (unsigned short*)(ws + 21233664); // 1,048,576 f
  float* Pbuf = winb_f;              // 2*16*2048*16 = 1,048,576 f (aliases winb, dead)
  float* hend = winb_f + 1048576;    // 1,048,576 f
  // total 23,330,816 floats = 93.3 MB

  // 1. LayerNorm -> bf16
  ln_kernel<<<M_, 256, 0, stream>>>(x, ln_g, ln_b, xnb);

  // 2. weight conversions fp32 -> bf16
  f2bf_kernel<<<4096, 256, 0, stream>>>((const float4*)in_proj_w, (u16x4*)winb);
  f2bf_kernel<<<2048, 256, 0, stream>>>((const float4*)out_proj_w, (u16x4*)woutb);

  // 3. in_proj (MFMA): xz = xn @ in_proj_w^T
  gemm_mfma<0><<<dim3(XZW_ / 128, M_ / 128), 256, 0, stream>>>(
      (const short*)xnb, DM_, (const short*)winb, DM_, xz, XZW_, DM_, nullptr, 0);

  // 4. conv + silu -> u
  conv_silu_kernel<<<dim3(DI_ / 256, L_ / LCH, B_), 256, 0, stream>>>(
      xz, conv_w, conv_b, u);

  // 5. x_proj split-K (partials into winb region, dead after in_proj) + reduce
  gemm_nt_sk<<<dim3(XDW_ / BN, M_ / BM, SK_), 256, 0, stream>>>(
      u, DI_, x_proj_w, DI_, winb_f, 96);
  reduce_sk<<<(M_ * XDW_) / 256, 256, 0, stream>>>(winb_f, xdbl);

  // 6. dt_proj + softplus
  gemm_nt<<<dim3(DI_ / BN, M_ / BM), 256, 0, stream>>>(
      xdbl, XDW_, dt_proj_w, DTR_, dlt, DI_, M_, DI_, DTR_, 1, dt_proj_b);

  // 7. chunked scan (Pbuf/hend alias winb region, dead after reduce_sk)
  scan_p1<<<dim3(DI_ / 64, B_, CH_), 256, 0, stream>>>(dlt, u, xdbl, A_log, Pbuf, hend);
  scan_p2<<<(B_ * DI_ * NS_) / 256, 256, 0, stream>>>(Pbuf, hend);
  scan_p3<<<dim3(DI_ / 64, B_, CH_), 256, 0, stream>>>(
      dlt, u, xdbl, A_log, Pbuf, xz, Dp, yb);

  // 8. out_proj (MFMA) + residual
  gemm_mfma<2><<<dim3(DM_ / 128, M_ / 128), 256, 0, stream>>>(
      (const short*)yb, DI_, (const short*)woutb, DI_, out, DM_, DI_, x, DM_);
}

// Round 9
// 285.931 us; speedup vs baseline: 3.8726x; 1.0597x over previous
//
#include <hip/hip_runtime.h>
#include <hip/hip_bf16.h>
#include <math.h>

#define B_   2
#define L_   1024
#define DM_  1024
#define DI_  2048
#define NS_  16
#define DTR_ 64
#define M_   (B_ * L_)          // 2048 rows
#define XZW_ (2 * DI_)          // 4096
#define XDW_ 128                // padded x_proj output width (dt|B|C|pad)
#define CH_  32                 // scan chunks
#define CLEN_ (L_ / CH_)        // 32
#define SK_  8                  // x_proj split-K chunks
#define KCH_ (DI_ / SK_)        // 256

typedef __attribute__((ext_vector_type(8))) short bf16x8;
typedef __attribute__((ext_vector_type(4))) float f32x4;
typedef __attribute__((ext_vector_type(4))) unsigned short u16x4;

static __device__ __forceinline__ unsigned short f2bf(float f) {
  __hip_bfloat16 h = __float2bfloat16(f);
  return *reinterpret_cast<unsigned short*>(&h);
}
static __device__ __forceinline__ float bf2f(unsigned short u) {
  unsigned int x = ((unsigned int)u) << 16;
  float f;
  __builtin_memcpy(&f, &x, 4);
  return f;
}

// ---------------- LayerNorm -> bf16 ----------------
__global__ __launch_bounds__(256) void ln_kernel(
    const float* __restrict__ x, const float* __restrict__ g,
    const float* __restrict__ b, unsigned short* __restrict__ xnb)
{
  int r = blockIdx.x;
  int t = threadIdx.x;
  const float4* xr = (const float4*)(x + (size_t)r * DM_);
  float4 v = xr[t];
  float s  = v.x + v.y + v.z + v.w;
  float ss = v.x * v.x + v.y * v.y + v.z * v.z + v.w * v.w;
  for (int m = 32; m >= 1; m >>= 1) {
    s  += __shfl_down(s, m);
    ss += __shfl_down(ss, m);
  }
  __shared__ float sb[4], ssb[4];
  int w = t >> 6, lane = t & 63;
  if (lane == 0) { sb[w] = s; ssb[w] = ss; }
  __syncthreads();
  s  = sb[0] + sb[1] + sb[2] + sb[3];
  ss = ssb[0] + ssb[1] + ssb[2] + ssb[3];
  float mu  = s * (1.f / DM_);
  float var = ss * (1.f / DM_) - mu * mu;
  float rs  = rsqrtf(var + 1e-5f);
  float4 gv = ((const float4*)g)[t];
  float4 bv = ((const float4*)b)[t];
  u16x4 o;
  o[0] = f2bf((v.x - mu) * rs * gv.x + bv.x);
  o[1] = f2bf((v.y - mu) * rs * gv.y + bv.y);
  o[2] = f2bf((v.z - mu) * rs * gv.z + bv.z);
  o[3] = f2bf((v.w - mu) * rs * gv.w + bv.w);
  ((u16x4*)xnb)[r * 256 + t] = o;
}

// ---------------- fp32 -> bf16 bulk convert ----------------
__global__ __launch_bounds__(256) void f2bf_kernel(
    const float4* __restrict__ in, u16x4* __restrict__ outp)
{
  int i = blockIdx.x * 256 + threadIdx.x;
  float4 v = in[i];
  u16x4 o;
  o[0] = f2bf(v.x); o[1] = f2bf(v.y); o[2] = f2bf(v.z); o[3] = f2bf(v.w);
  outp[i] = o;
}

// ---------------- bf16 MFMA GEMM NT: C[m,n] = sum_k A[m,k]*Bw[n,k] ----------------
// 128x128 tile, BK=64, 4 waves. LDS XOR-swizzled via pre-swizzled global source
// (linear global_load_lds dest). MODE 0: store ; MODE 2: store + res.
template<int MODE>
__global__ __launch_bounds__(256) void gemm_mfma(
    const short* __restrict__ A, int lda,
    const short* __restrict__ Bw, int ldb,
    float* __restrict__ C, int ldc, int Kdim,
    const float* __restrict__ res, int ldres)
{
  __shared__ __align__(16) short As[128 * 64];
  __shared__ __align__(16) short Bs[128 * 64];
  const int bm = blockIdx.y * 128, bn = blockIdx.x * 128;
  const int t = threadIdx.x, wid = t >> 6, lane = t & 63;
  const int wr = wid >> 1, wc = wid & 1;

  f32x4 acc[4][4];
#pragma unroll
  for (int i = 0; i < 4; ++i)
#pragma unroll
    for (int j = 0; j < 4; ++j) acc[i][j] = (f32x4){0.f, 0.f, 0.f, 0.f};

  const int srow = wid * 8 + (lane >> 3);
  const int sc   = lane & 7;
  const int r16 = lane & 15, khalf = lane >> 4;

  for (int k0 = 0; k0 < Kdim; k0 += 64) {
#pragma unroll
    for (int q = 0; q < 4; ++q) {
      int row = q * 32 + srow;
      int csw = sc ^ (row & 7);
      const short* gA = A + (size_t)(bm + row) * lda + k0 + csw * 8;
      const short* gB = Bw + (size_t)(bn + row) * ldb + k0 + csw * 8;
      __builtin_amdgcn_global_load_lds(
          (const __attribute__((address_space(1))) void*)gA,
          (__attribute__((address_space(3))) void*)(As + q * 2048 + wid * 512),
          16, 0, 0);
      __builtin_amdgcn_global_load_lds(
          (const __attribute__((address_space(1))) void*)gB,
          (__attribute__((address_space(3))) void*)(Bs + q * 2048 + wid * 512),
          16, 0, 0);
    }
    __syncthreads();

    bf16x8 af[4][2], bf[4][2];
#pragma unroll
    for (int m = 0; m < 4; ++m) {
#pragma unroll
      for (int kk = 0; kk < 2; ++kk) {
        int c16 = kk * 4 + khalf;
        int rowa = wr * 64 + m * 16 + r16;
        int rowb = wc * 64 + m * 16 + r16;
        af[m][kk] = *(const bf16x8*)(As + rowa * 64 + ((c16 ^ (rowa & 7)) << 3));
        bf[m][kk] = *(const bf16x8*)(Bs + rowb * 64 + ((c16 ^ (rowb & 7)) << 3));
      }
    }
#pragma unroll
    for (int kk = 0; kk < 2; ++kk)
#pragma unroll
      for (int m = 0; m < 4; ++m)
#pragma unroll
        for (int nn = 0; nn < 4; ++nn)
          acc[m][nn] = __builtin_amdgcn_mfma_f32_16x16x32_bf16(
              af[m][kk], bf[nn][kk], acc[m][nn], 0, 0, 0);
    __syncthreads();
  }

  const int rgrp = lane >> 4;
#pragma unroll
  for (int m = 0; m < 4; ++m)
#pragma unroll
    for (int nn = 0; nn < 4; ++nn) {
      int col = bn + wc * 64 + nn * 16 + r16;
#pragma unroll
      for (int rg = 0; rg < 4; ++rg) {
        int row = bm + wr * 64 + m * 16 + rgrp * 4 + rg;
        float v = acc[m][nn][rg];
        if (MODE == 2) v += res[(size_t)row * ldres + col];
        C[(size_t)row * ldc + col] = v;
      }
    }
}

// ---------------- fp32 tiled NT GEMM ----------------
// mode 0: store acc ; mode 1: store softplus(acc + bias[n])
#define BM 64
#define BN 64
#define BK 32
#define PADR 68

__global__ __launch_bounds__(256) void gemm_nt(
    const float* __restrict__ A, int lda,
    const float* __restrict__ Bw, int ldb,
    float* __restrict__ C, int ldc,
    int Mrows, int Ncols, int Kdim,
    int mode, const float* __restrict__ bias)
{
  __shared__ float as[BK][PADR];
  __shared__ float bs[BK][PADR];
  int bm = blockIdx.y * BM;
  int bn = blockIdx.x * BN;
  int t  = threadIdx.x;
  int tx = t & 15, ty = t >> 4;

  float acc[4][4] = {};

  int m0 = t >> 3;
  int kq = t & 7;
  const float4 z4 = {0.f, 0.f, 0.f, 0.f};

  for (int k0 = 0; k0 < Kdim; k0 += BK) {
    float4 a0 = *(const float4*)(A + (size_t)(bm + m0) * lda + k0 + kq * 4);
    float4 a1 = *(const float4*)(A + (size_t)(bm + m0 + 32) * lda + k0 + kq * 4);
    float4 b0 = (bn + m0 < Ncols)
        ? *(const float4*)(Bw + (size_t)(bn + m0) * ldb + k0 + kq * 4) : z4;
    float4 b1 = (bn + m0 + 32 < Ncols)
        ? *(const float4*)(Bw + (size_t)(bn + m0 + 32) * ldb + k0 + kq * 4) : z4;
    as[kq * 4 + 0][m0] = a0.x;  as[kq * 4 + 1][m0] = a0.y;
    as[kq * 4 + 2][m0] = a0.z;  as[kq * 4 + 3][m0] = a0.w;
    as[kq * 4 + 0][m0 + 32] = a1.x;  as[kq * 4 + 1][m0 + 32] = a1.y;
    as[kq * 4 + 2][m0 + 32] = a1.z;  as[kq * 4 + 3][m0 + 32] = a1.w;
    bs[kq * 4 + 0][m0] = b0.x;  bs[kq * 4 + 1][m0] = b0.y;
    bs[kq * 4 + 2][m0] = b0.z;  bs[kq * 4 + 3][m0] = b0.w;
    bs[kq * 4 + 0][m0 + 32] = b1.x;  bs[kq * 4 + 1][m0 + 32] = b1.y;
    bs[kq * 4 + 2][m0 + 32] = b1.z;  bs[kq * 4 + 3][m0 + 32] = b1.w;
    __syncthreads();

#pragma unroll
    for (int kk = 0; kk < BK; ++kk) {
      float4 a4 = *(const float4*)&as[kk][ty * 4];
      float4 b4 = *(const float4*)&bs[kk][tx * 4];
      float ar[4] = {a4.x, a4.y, a4.z, a4.w};
      float br[4] = {b4.x, b4.y, b4.z, b4.w};
#pragma unroll
      for (int i = 0; i < 4; ++i)
#pragma unroll
        for (int j = 0; j < 4; ++j)
          acc[i][j] = fmaf(ar[i], br[j], acc[i][j]);
    }
    __syncthreads();
  }

#pragma unroll
  for (int i = 0; i < 4; ++i) {
    int r = bm + ty * 4 + i;
    int c = bn + tx * 4;
    float vv[4];
#pragma unroll
    for (int j = 0; j < 4; ++j) {
      float v = acc[i][j];
      if (mode == 1) {
        v += bias[c + j];
        v = (v > 20.f) ? v : log1pf(expf(v));
      }
      vv[j] = v;
    }
    float4 o = {vv[0], vv[1], vv[2], vv[3]};
    *(float4*)(C + (size_t)r * ldc + c) = o;
  }
}

// ---------------- split-K fp32 NT GEMM for x_proj ----------------
__global__ __launch_bounds__(256) void gemm_nt_sk(
    const float* __restrict__ A, int lda,
    const float* __restrict__ Bw, int ldb,
    float* __restrict__ part, int Ncols)
{
  __shared__ float as[BK][PADR];
  __shared__ float bs[BK][PADR];
  int bm = blockIdx.y * BM;
  int bn = blockIdx.x * BN;
  int sk = blockIdx.z;
  int t  = threadIdx.x;
  int tx = t & 15, ty = t >> 4;

  float acc[4][4] = {};

  int m0 = t >> 3;
  int kq = t & 7;
  const float4 z4 = {0.f, 0.f, 0.f, 0.f};

  for (int k0 = sk * KCH_; k0 < (sk + 1) * KCH_; k0 += BK) {
    float4 a0 = *(const float4*)(A + (size_t)(bm + m0) * lda + k0 + kq * 4);
    float4 a1 = *(const float4*)(A + (size_t)(bm + m0 + 32) * lda + k0 + kq * 4);
    float4 b0 = (bn + m0 < Ncols)
        ? *(const float4*)(Bw + (size_t)(bn + m0) * ldb + k0 + kq * 4) : z4;
    float4 b1 = (bn + m0 + 32 < Ncols)
        ? *(const float4*)(Bw + (size_t)(bn + m0 + 32) * ldb + k0 + kq * 4) : z4;
    as[kq * 4 + 0][m0] = a0.x;  as[kq * 4 + 1][m0] = a0.y;
    as[kq * 4 + 2][m0] = a0.z;  as[kq * 4 + 3][m0] = a0.w;
    as[kq * 4 + 0][m0 + 32] = a1.x;  as[kq * 4 + 1][m0 + 32] = a1.y;
    as[kq * 4 + 2][m0 + 32] = a1.z;  as[kq * 4 + 3][m0 + 32] = a1.w;
    bs[kq * 4 + 0][m0] = b0.x;  bs[kq * 4 + 1][m0] = b0.y;
    bs[kq * 4 + 2][m0] = b0.z;  bs[kq * 4 + 3][m0] = b0.w;
    bs[kq * 4 + 0][m0 + 32] = b1.x;  bs[kq * 4 + 1][m0 + 32] = b1.y;
    bs[kq * 4 + 2][m0 + 32] = b1.z;  bs[kq * 4 + 3][m0 + 32] = b1.w;
    __syncthreads();

#pragma unroll
    for (int kk = 0; kk < BK; ++kk) {
      float4 a4 = *(const float4*)&as[kk][ty * 4];
      float4 b4 = *(const float4*)&bs[kk][tx * 4];
      float ar[4] = {a4.x, a4.y, a4.z, a4.w};
      float br[4] = {b4.x, b4.y, b4.z, b4.w};
#pragma unroll
      for (int i = 0; i < 4; ++i)
#pragma unroll
        for (int j = 0; j < 4; ++j)
          acc[i][j] = fmaf(ar[i], br[j], acc[i][j]);
    }
    __syncthreads();
  }

  float* outp = part + (size_t)sk * M_ * XDW_;
#pragma unroll
  for (int i = 0; i < 4; ++i) {
    int r = bm + ty * 4 + i;
    int c = bn + tx * 4;
    float4 o = {acc[i][0], acc[i][1], acc[i][2], acc[i][3]};
    *(float4*)(outp + (size_t)r * XDW_ + c) = o;
  }
}

// reduce partials: xdbl[i] = sum_sk part[sk][i]
__global__ __launch_bounds__(256) void reduce_sk(
    const float* __restrict__ part, float* __restrict__ xdbl)
{
  int i = blockIdx.x * 256 + threadIdx.x;
  float s = 0.f;
#pragma unroll
  for (int sk = 0; sk < SK_; ++sk) s += part[(size_t)sk * M_ * XDW_ + i];
  xdbl[i] = s;
}

// ---------------- depthwise causal conv (K=4) + SiLU ----------------
#define LCH 32
__global__ __launch_bounds__(256) void conv_silu_kernel(
    const float* __restrict__ xz, const float* __restrict__ cw,
    const float* __restrict__ cb, float* __restrict__ u)
{
  int d  = blockIdx.x * 256 + threadIdx.x;
  int l0 = blockIdx.y * LCH;
  int b  = blockIdx.z;
  float w0 = cw[d * 4 + 0], w1 = cw[d * 4 + 1];
  float w2 = cw[d * 4 + 2], w3 = cw[d * 4 + 3];
  float bias = cb[d];
  const float* xi = xz + (size_t)(b * L_) * XZW_ + d;
  float x3 = (l0 >= 3) ? xi[(size_t)(l0 - 3) * XZW_] : 0.f;
  float x2 = (l0 >= 2) ? xi[(size_t)(l0 - 2) * XZW_] : 0.f;
  float x1 = (l0 >= 1) ? xi[(size_t)(l0 - 1) * XZW_] : 0.f;
  for (int l = l0; l < l0 + LCH; ++l) {
    float x0 = xi[(size_t)l * XZW_];
    float v = w0 * x3 + w1 * x2 + w2 * x1 + w3 * x0 + bias;
    float uu = v / (1.f + __expf(-v));
    u[((size_t)(b * L_) + l) * DI_ + d] = uu;
    x3 = x2; x2 = x1; x1 = x0;
  }
}

// ---------------- chunked selective scan (4 states/lane, 4 lanes/channel) ----
// thread t: ng = t&3 (n-group of 4), dl = t>>2 (0..63); d = bx*64+dl
// grid (DI/64, B, CH)
__global__ __launch_bounds__(256) void scan_p1(
    const float* __restrict__ dlt, const float* __restrict__ u,
    const float* __restrict__ xdbl, const float* __restrict__ A_log,
    float* __restrict__ Pbuf, unsigned short* __restrict__ hend)
{
  int t = threadIdx.x;
  int ng = t & 3, dl = t >> 2;
  int d = blockIdx.x * 64 + dl;
  int b = blockIdx.y;
  int c = blockIdx.z;
  int l0 = c * CLEN_;
  float4 Al = *(const float4*)(A_log + d * NS_ + ng * 4);
  float A0 = -__expf(Al.x), A1 = -__expf(Al.y), A2 = -__expf(Al.z), A3 = -__expf(Al.w);
  float h0 = 0.f, h1 = 0.f, h2 = 0.f, h3 = 0.f, S = 0.f;
  const float* dp = dlt + ((size_t)(b * L_) + l0) * DI_ + d;
  const float* up = u   + ((size_t)(b * L_) + l0) * DI_ + d;
  const float* xp = xdbl + ((size_t)(b * L_) + l0) * XDW_ + DTR_ + ng * 4;
  float dv = dp[0], uv = up[0];
  float4 Bv = *(const float4*)xp;
  for (int l = 0; l < CLEN_; ++l) {
    int ln = (l + 1 < CLEN_) ? l + 1 : l;
    float dv_n = dp[(size_t)ln * DI_];
    float uv_n = up[(size_t)ln * DI_];
    float4 Bv_n = *(const float4*)(xp + (size_t)ln * XDW_);
    float dvu = dv * uv;
    h0 = __expf(dv * A0) * h0 + dvu * Bv.x;
    h1 = __expf(dv * A1) * h1 + dvu * Bv.y;
    h2 = __expf(dv * A2) * h2 + dvu * Bv.z;
    h3 = __expf(dv * A3) * h3 + dvu * Bv.w;
    S += dv;
    dv = dv_n; uv = uv_n; Bv = Bv_n;
  }
  size_t i = ((size_t)((b * CH_ + c) * DI_) + d) * NS_ + ng * 4;
  float4 P; P.x = __expf(S * A0); P.y = __expf(S * A1);
  P.z = __expf(S * A2); P.w = __expf(S * A3);
  u16x4 H; H[0] = f2bf(h0); H[1] = f2bf(h1); H[2] = f2bf(h2); H[3] = f2bf(h3);
  *(float4*)(Pbuf + i) = P;
  *(u16x4*)(hend + i) = H;
}

__global__ __launch_bounds__(256) void scan_p2(
    float* __restrict__ Pbuf, const unsigned short* __restrict__ hend)
{
  int tid = blockIdx.x * 256 + threadIdx.x;   // over B*DI*NS = 65536
  int n = tid & 15;
  int d = (tid >> 4) & (DI_ - 1);
  int b = tid >> 15;
  float h = 0.f;
  for (int c = 0; c < CH_; ++c) {
    size_t i = ((size_t)((b * CH_ + c) * DI_) + d) * NS_ + n;
    float Pv = Pbuf[i];
    float he = bf2f(hend[i]);
    Pbuf[i] = h;
    h = Pv * h + he;
  }
}

__global__ __launch_bounds__(256) void scan_p3(
    const float* __restrict__ dlt, const float* __restrict__ u,
    const float* __restrict__ xdbl, const float* __restrict__ A_log,
    const float* __restrict__ hin, const float* __restrict__ xz,
    const float* __restrict__ Dp, unsigned short* __restrict__ yb)
{
  int t = threadIdx.x;
  int ng = t & 3, dl = t >> 2;
  int d = blockIdx.x * 64 + dl;
  int b = blockIdx.y;
  int c = blockIdx.z;
  int l0 = c * CLEN_;
  float4 Al = *(const float4*)(A_log + d * NS_ + ng * 4);
  float A0 = -__expf(Al.x), A1 = -__expf(Al.y), A2 = -__expf(Al.z), A3 = -__expf(Al.w);
  size_t i0 = ((size_t)((b * CH_ + c) * DI_) + d) * NS_ + ng * 4;
  float4 hv = *(const float4*)(hin + i0);
  float h0 = hv.x, h1 = hv.y, h2 = hv.z, h3 = hv.w;
  float Dd = Dp[d];
  const float* dp = dlt + ((size_t)(b * L_) + l0) * DI_ + d;
  const float* up = u   + ((size_t)(b * L_) + l0) * DI_ + d;
  const float* xp = xdbl + ((size_t)(b * L_) + l0) * XDW_ + DTR_ + ng * 4;
  const float* zp = xz + ((size_t)(b * L_) + l0) * XZW_ + DI_ + d;
  unsigned short* yp = yb + ((size_t)(b * L_) + l0) * DI_ + d;
  float dv = dp[0], uv = up[0];
  float4 Bv = *(const float4*)xp;
  float4 Cv = *(const float4*)(xp + NS_);
  for (int l = 0; l < CLEN_; ++l) {
    int ln = (l + 1 < CLEN_) ? l + 1 : l;
    float dv_n = dp[(size_t)ln * DI_];
    float uv_n = up[(size_t)ln * DI_];
    float4 Bv_n = *(const float4*)(xp + (size_t)ln * XDW_);
    float4 Cv_n = *(const float4*)(xp + (size_t)ln * XDW_ + NS_);
    float dvu = dv * uv;
    h0 = __expf(dv * A0) * h0 + dvu * Bv.x;
    h1 = __expf(dv * A1) * h1 + dvu * Bv.y;
    h2 = __expf(dv * A2) * h2 + dvu * Bv.z;
    h3 = __expf(dv * A3) * h3 + dvu * Bv.w;
    float py = h0 * Cv.x + h1 * Cv.y + h2 * Cv.z + h3 * Cv.w;
    py += __shfl_xor(py, 1);
    py += __shfl_xor(py, 2);
    if (ng == 0) {
      float z = zp[(size_t)l * XZW_];
      float zs = z / (1.f + __expf(-z));
      yp[(size_t)l * DI_] = f2bf((py + uv * Dd) * zs);
    }
    dv = dv_n; uv = uv_n; Bv = Bv_n; Cv = Cv_n;
  }
}

extern "C" void kernel_launch(void* const* d_in, const int* in_sizes, int n_in,
                              void* d_out, int out_size, void* d_ws, size_t ws_size,
                              hipStream_t stream)
{
  const float* x         = (const float*)d_in[0];
  const float* ln_g      = (const float*)d_in[1];
  const float* ln_b      = (const float*)d_in[2];
  const float* in_proj_w = (const float*)d_in[3];
  const float* conv_w    = (const float*)d_in[4];
  const float* conv_b    = (const float*)d_in[5];
  const float* x_proj_w  = (const float*)d_in[6];
  const float* dt_proj_w = (const float*)d_in[7];
  const float* dt_proj_b = (const float*)d_in[8];
  const float* A_log     = (const float*)d_in[9];
  const float* Dp        = (const float*)d_in[10];
  const float* out_proj_w= (const float*)d_in[11];
  float* out = (float*)d_out;

  float* ws = (float*)d_ws;
  float* xz   = ws;                  // 2048*4096          = 8,388,608 f
  float* u    = ws + 8388608;        // 2048*2048          = 4,194,304 f
  float* xdbl = ws + 12582912;       // 2048*128           =   262,144 f
  float* dlt  = ws + 12845056;       // 2048*2048          = 4,194,304 f
  unsigned short* xnb   = (unsigned short*)(ws + 17039360); // 1,048,576 f region
  float* winb_f = ws + 18087936;     // 2,097,152 f: winb bf16 / sk-partials / Pbuf
  unsigned short* winb  = (unsigned short*)winb_f;
  unsigned short* woutb = (unsigned short*)(ws + 20185088); // 1,048,576 f
  unsigned short* yb    = (unsigned short*)(ws + 21233664); // 1,048,576 f
  // scan boundary buffers (aliases of dead regions):
  float* Pbuf = winb_f;                       // 2*32*2048*16 = 2,097,152 f (fits exactly)
  unsigned short* hendb = xnb;                // 2,097,152 bf16 (fits xnb region exactly)
  // total 23,330,816 floats = 93.3 MB

  // 1. LayerNorm -> bf16
  ln_kernel<<<M_, 256, 0, stream>>>(x, ln_g, ln_b, xnb);

  // 2. weight conversions fp32 -> bf16
  f2bf_kernel<<<4096, 256, 0, stream>>>((const float4*)in_proj_w, (u16x4*)winb);
  f2bf_kernel<<<2048, 256, 0, stream>>>((const float4*)out_proj_w, (u16x4*)woutb);

  // 3. in_proj (MFMA): xz = xn @ in_proj_w^T
  gemm_mfma<0><<<dim3(XZW_ / 128, M_ / 128), 256, 0, stream>>>(
      (const short*)xnb, DM_, (const short*)winb, DM_, xz, XZW_, DM_, nullptr, 0);

  // 4. conv + silu -> u
  conv_silu_kernel<<<dim3(DI_ / 256, L_ / LCH, B_), 256, 0, stream>>>(
      xz, conv_w, conv_b, u);

  // 5. x_proj split-K (partials into winb region, dead after in_proj) + reduce
  gemm_nt_sk<<<dim3(XDW_ / BN, M_ / BM, SK_), 256, 0, stream>>>(
      u, DI_, x_proj_w, DI_, winb_f, 96);
  reduce_sk<<<(M_ * XDW_) / 256, 256, 0, stream>>>(winb_f, xdbl);

  // 6. dt_proj + softplus
  gemm_nt<<<dim3(DI_ / BN, M_ / BM), 256, 0, stream>>>(
      xdbl, XDW_, dt_proj_w, DTR_, dlt, DI_, M_, DI_, DTR_, 1, dt_proj_b);

  // 7. chunked scan (Pbuf aliases winb; hend bf16 aliases xnb — both dead now)
  scan_p1<<<dim3(DI_ / 64, B_, CH_), 256, 0, stream>>>(dlt, u, xdbl, A_log, Pbuf, hendb);
  scan_p2<<<(B_ * DI_ * NS_) / 256, 256, 0, stream>>>(Pbuf, hendb);
  scan_p3<<<dim3(DI_ / 64, B_, CH_), 256, 0, stream>>>(
      dlt, u, xdbl, A_log, Pbuf, xz, Dp, yb);

  // 8. out_proj (MFMA) + residual
  gemm_mfma<2><<<dim3(DM_ / 128, M_ / 128), 256, 0, stream>>>(
      (const short*)yb, DI_, (const short*)woutb, DI_, out, DM_, DI_, x, DM_);
}

// Round 10
// 273.299 us; speedup vs baseline: 4.0516x; 1.0462x over previous
//
#include <hip/hip_runtime.h>
#include <hip/hip_bf16.h>
#include <math.h>

#define B_   2
#define L_   1024
#define DM_  1024
#define DI_  2048
#define NS_  16
#define DTR_ 64
#define M_   (B_ * L_)          // 2048 rows
#define XZW_ (2 * DI_)          // 4096
#define XDW_ 128                // padded x_proj output width (dt|B|C|pad)
#define CH_  32                 // scan chunks
#define CLEN_ (L_ / CH_)        // 32
#define SK_  8                  // x_proj split-K chunks
#define KCH_ (DI_ / SK_)        // 256

typedef __attribute__((ext_vector_type(8))) short bf16x8;
typedef __attribute__((ext_vector_type(4))) float f32x4;
typedef __attribute__((ext_vector_type(4))) unsigned short u16x4;

static __device__ __forceinline__ unsigned short f2bf(float f) {
  __hip_bfloat16 h = __float2bfloat16(f);
  return *reinterpret_cast<unsigned short*>(&h);
}
static __device__ __forceinline__ float bf2f(unsigned short u) {
  unsigned int x = ((unsigned int)u) << 16;
  float f;
  __builtin_memcpy(&f, &x, 4);
  return f;
}

// ---------------- LayerNorm -> bf16 ----------------
__global__ __launch_bounds__(256) void ln_kernel(
    const float* __restrict__ x, const float* __restrict__ g,
    const float* __restrict__ b, unsigned short* __restrict__ xnb)
{
  int r = blockIdx.x;
  int t = threadIdx.x;
  const float4* xr = (const float4*)(x + (size_t)r * DM_);
  float4 v = xr[t];
  float s  = v.x + v.y + v.z + v.w;
  float ss = v.x * v.x + v.y * v.y + v.z * v.z + v.w * v.w;
  for (int m = 32; m >= 1; m >>= 1) {
    s  += __shfl_down(s, m);
    ss += __shfl_down(ss, m);
  }
  __shared__ float sb[4], ssb[4];
  int w = t >> 6, lane = t & 63;
  if (lane == 0) { sb[w] = s; ssb[w] = ss; }
  __syncthreads();
  s  = sb[0] + sb[1] + sb[2] + sb[3];
  ss = ssb[0] + ssb[1] + ssb[2] + ssb[3];
  float mu  = s * (1.f / DM_);
  float var = ss * (1.f / DM_) - mu * mu;
  float rs  = rsqrtf(var + 1e-5f);
  float4 gv = ((const float4*)g)[t];
  float4 bv = ((const float4*)b)[t];
  u16x4 o;
  o[0] = f2bf((v.x - mu) * rs * gv.x + bv.x);
  o[1] = f2bf((v.y - mu) * rs * gv.y + bv.y);
  o[2] = f2bf((v.z - mu) * rs * gv.z + bv.z);
  o[3] = f2bf((v.w - mu) * rs * gv.w + bv.w);
  ((u16x4*)xnb)[r * 256 + t] = o;
}

// ---------------- fp32 -> bf16 bulk convert ----------------
__global__ __launch_bounds__(256) void f2bf_kernel(
    const float4* __restrict__ in, u16x4* __restrict__ outp)
{
  int i = blockIdx.x * 256 + threadIdx.x;
  float4 v = in[i];
  u16x4 o;
  o[0] = f2bf(v.x); o[1] = f2bf(v.y); o[2] = f2bf(v.z); o[3] = f2bf(v.w);
  outp[i] = o;
}

// ---------------- bf16 MFMA GEMM NT with 2-phase double-buffered prefetch ----
// TM=128 fixed; TN in {128, 64}. 4 waves.
// TN=128: waves 2x2, wave tile 64x64, acc[4][4]. TN=64: waves 4x1, wave 32x64, acc[2][4].
// LDS XOR-swizzled via pre-swizzled global source (linear global_load_lds dest).
// Pipeline: STAGE(buf0); loop { barrier; STAGE(buf^1,t+1); COMPUTE(buf); swap; }
// -> one barrier per K-step; prefetch latency hidden under ds_read+MFMA.
// MODE 0: store ; MODE 2: store + res.
template<int MODE, int TN>
__global__ __launch_bounds__(256) void gemm_mfma(
    const short* __restrict__ A, int lda,
    const short* __restrict__ Bw, int ldb,
    float* __restrict__ C, int ldc, int Kdim,
    const float* __restrict__ res, int ldres)
{
  constexpr int MREP = (TN == 128) ? 4 : 2;
  constexpr int NREP = 4;
  constexpr int WM   = (TN == 128) ? 64 : 32;
  __shared__ __align__(16) short As[2][128 * 64];
  __shared__ __align__(16) short Bs[2][TN * 64];
  const int bm = blockIdx.y * 128, bn = blockIdx.x * TN;
  const int t = threadIdx.x, wid = t >> 6, lane = t & 63;
  const int wr = (TN == 128) ? (wid >> 1) : wid;
  const int wc = (TN == 128) ? (wid & 1) : 0;

  f32x4 acc[MREP][NREP];
#pragma unroll
  for (int i = 0; i < MREP; ++i)
#pragma unroll
    for (int j = 0; j < NREP; ++j) acc[i][j] = (f32x4){0.f, 0.f, 0.f, 0.f};

  const int srow = wid * 8 + (lane >> 3);   // row within 32-row stage group
  const int sc   = lane & 7;                // linear k-word slot
  const int r16 = lane & 15, khalf = lane >> 4;

  auto STAGE = [&](int buf, int k0) {
#pragma unroll
    for (int q = 0; q < 4; ++q) {
      int row = q * 32 + srow;
      int csw = sc ^ (row & 7);
      const short* gA = A + (size_t)(bm + row) * lda + k0 + csw * 8;
      __builtin_amdgcn_global_load_lds(
          (const __attribute__((address_space(1))) void*)gA,
          (__attribute__((address_space(3))) void*)(&As[buf][q * 2048 + wid * 512]),
          16, 0, 0);
    }
#pragma unroll
    for (int q = 0; q < TN / 32; ++q) {
      int row = q * 32 + srow;
      int csw = sc ^ (row & 7);
      const short* gB = Bw + (size_t)(bn + row) * ldb + k0 + csw * 8;
      __builtin_amdgcn_global_load_lds(
          (const __attribute__((address_space(1))) void*)gB,
          (__attribute__((address_space(3))) void*)(&Bs[buf][q * 2048 + wid * 512]),
          16, 0, 0);
    }
  };

  const int nt = Kdim >> 6;
  STAGE(0, 0);
  int cur = 0;
  for (int ti = 0; ti < nt; ++ti) {
    __syncthreads();                         // buf[cur] ready (vmcnt drained here)
    if (ti + 1 < nt) STAGE(cur ^ 1, (ti + 1) << 6);   // prefetch overlaps compute

    bf16x8 af[MREP][2], bfr[NREP][2];
#pragma unroll
    for (int m = 0; m < MREP; ++m)
#pragma unroll
      for (int kk = 0; kk < 2; ++kk) {
        int c16 = kk * 4 + khalf;
        int rowa = wr * WM + m * 16 + r16;
        af[m][kk] = *(const bf16x8*)(&As[cur][rowa * 64 + ((c16 ^ (rowa & 7)) << 3)]);
      }
#pragma unroll
    for (int nn = 0; nn < NREP; ++nn)
#pragma unroll
      for (int kk = 0; kk < 2; ++kk) {
        int c16 = kk * 4 + khalf;
        int rowb = wc * 64 + nn * 16 + r16;
        bfr[nn][kk] = *(const bf16x8*)(&Bs[cur][rowb * 64 + ((c16 ^ (rowb & 7)) << 3)]);
      }
#pragma unroll
    for (int kk = 0; kk < 2; ++kk)
#pragma unroll
      for (int m = 0; m < MREP; ++m)
#pragma unroll
        for (int nn = 0; nn < NREP; ++nn)
          acc[m][nn] = __builtin_amdgcn_mfma_f32_16x16x32_bf16(
              af[m][kk], bfr[nn][kk], acc[m][nn], 0, 0, 0);
    cur ^= 1;
  }

  const int rgrp = lane >> 4;
#pragma unroll
  for (int m = 0; m < MREP; ++m)
#pragma unroll
    for (int nn = 0; nn < NREP; ++nn) {
      int col = bn + wc * 64 + nn * 16 + r16;
#pragma unroll
      for (int rg = 0; rg < 4; ++rg) {
        int row = bm + wr * WM + m * 16 + rgrp * 4 + rg;
        float v = acc[m][nn][rg];
        if (MODE == 2) v += res[(size_t)row * ldres + col];
        C[(size_t)row * ldc + col] = v;
      }
    }
}

// ---------------- fp32 tiled NT GEMM ----------------
// mode 0: store acc ; mode 1: store softplus(acc + bias[n])
#define BM 64
#define BN 64
#define BK 32
#define PADR 68

__global__ __launch_bounds__(256) void gemm_nt(
    const float* __restrict__ A, int lda,
    const float* __restrict__ Bw, int ldb,
    float* __restrict__ C, int ldc,
    int Mrows, int Ncols, int Kdim,
    int mode, const float* __restrict__ bias)
{
  __shared__ float as[BK][PADR];
  __shared__ float bs[BK][PADR];
  int bm = blockIdx.y * BM;
  int bn = blockIdx.x * BN;
  int t  = threadIdx.x;
  int tx = t & 15, ty = t >> 4;

  float acc[4][4] = {};

  int m0 = t >> 3;
  int kq = t & 7;
  const float4 z4 = {0.f, 0.f, 0.f, 0.f};

  for (int k0 = 0; k0 < Kdim; k0 += BK) {
    float4 a0 = *(const float4*)(A + (size_t)(bm + m0) * lda + k0 + kq * 4);
    float4 a1 = *(const float4*)(A + (size_t)(bm + m0 + 32) * lda + k0 + kq * 4);
    float4 b0 = (bn + m0 < Ncols)
        ? *(const float4*)(Bw + (size_t)(bn + m0) * ldb + k0 + kq * 4) : z4;
    float4 b1 = (bn + m0 + 32 < Ncols)
        ? *(const float4*)(Bw + (size_t)(bn + m0 + 32) * ldb + k0 + kq * 4) : z4;
    as[kq * 4 + 0][m0] = a0.x;  as[kq * 4 + 1][m0] = a0.y;
    as[kq * 4 + 2][m0] = a0.z;  as[kq * 4 + 3][m0] = a0.w;
    as[kq * 4 + 0][m0 + 32] = a1.x;  as[kq * 4 + 1][m0 + 32] = a1.y;
    as[kq * 4 + 2][m0 + 32] = a1.z;  as[kq * 4 + 3][m0 + 32] = a1.w;
    bs[kq * 4 + 0][m0] = b0.x;  bs[kq * 4 + 1][m0] = b0.y;
    bs[kq * 4 + 2][m0] = b0.z;  bs[kq * 4 + 3][m0] = b0.w;
    bs[kq * 4 + 0][m0 + 32] = b1.x;  bs[kq * 4 + 1][m0 + 32] = b1.y;
    bs[kq * 4 + 2][m0 + 32] = b1.z;  bs[kq * 4 + 3][m0 + 32] = b1.w;
    __syncthreads();

#pragma unroll
    for (int kk = 0; kk < BK; ++kk) {
      float4 a4 = *(const float4*)&as[kk][ty * 4];
      float4 b4 = *(const float4*)&bs[kk][tx * 4];
      float ar[4] = {a4.x, a4.y, a4.z, a4.w};
      float br[4] = {b4.x, b4.y, b4.z, b4.w};
#pragma unroll
      for (int i = 0; i < 4; ++i)
#pragma unroll
        for (int j = 0; j < 4; ++j)
          acc[i][j] = fmaf(ar[i], br[j], acc[i][j]);
    }
    __syncthreads();
  }

#pragma unroll
  for (int i = 0; i < 4; ++i) {
    int r = bm + ty * 4 + i;
    int c = bn + tx * 4;
    float vv[4];
#pragma unroll
    for (int j = 0; j < 4; ++j) {
      float v = acc[i][j];
      if (mode == 1) {
        v += bias[c + j];
        v = (v > 20.f) ? v : log1pf(expf(v));
      }
      vv[j] = v;
    }
    float4 o = {vv[0], vv[1], vv[2], vv[3]};
    *(float4*)(C + (size_t)r * ldc + c) = o;
  }
}

// ---------------- split-K fp32 NT GEMM for x_proj ----------------
__global__ __launch_bounds__(256) void gemm_nt_sk(
    const float* __restrict__ A, int lda,
    const float* __restrict__ Bw, int ldb,
    float* __restrict__ part, int Ncols)
{
  __shared__ float as[BK][PADR];
  __shared__ float bs[BK][PADR];
  int bm = blockIdx.y * BM;
  int bn = blockIdx.x * BN;
  int sk = blockIdx.z;
  int t  = threadIdx.x;
  int tx = t & 15, ty = t >> 4;

  float acc[4][4] = {};

  int m0 = t >> 3;
  int kq = t & 7;
  const float4 z4 = {0.f, 0.f, 0.f, 0.f};

  for (int k0 = sk * KCH_; k0 < (sk + 1) * KCH_; k0 += BK) {
    float4 a0 = *(const float4*)(A + (size_t)(bm + m0) * lda + k0 + kq * 4);
    float4 a1 = *(const float4*)(A + (size_t)(bm + m0 + 32) * lda + k0 + kq * 4);
    float4 b0 = (bn + m0 < Ncols)
        ? *(const float4*)(Bw + (size_t)(bn + m0) * ldb + k0 + kq * 4) : z4;
    float4 b1 = (bn + m0 + 32 < Ncols)
        ? *(const float4*)(Bw + (size_t)(bn + m0 + 32) * ldb + k0 + kq * 4) : z4;
    as[kq * 4 + 0][m0] = a0.x;  as[kq * 4 + 1][m0] = a0.y;
    as[kq * 4 + 2][m0] = a0.z;  as[kq * 4 + 3][m0] = a0.w;
    as[kq * 4 + 0][m0 + 32] = a1.x;  as[kq * 4 + 1][m0 + 32] = a1.y;
    as[kq * 4 + 2][m0 + 32] = a1.z;  as[kq * 4 + 3][m0 + 32] = a1.w;
    bs[kq * 4 + 0][m0] = b0.x;  bs[kq * 4 + 1][m0] = b0.y;
    bs[kq * 4 + 2][m0] = b0.z;  bs[kq * 4 + 3][m0] = b0.w;
    bs[kq * 4 + 0][m0 + 32] = b1.x;  bs[kq * 4 + 1][m0 + 32] = b1.y;
    bs[kq * 4 + 2][m0 + 32] = b1.z;  bs[kq * 4 + 3][m0 + 32] = b1.w;
    __syncthreads();

#pragma unroll
    for (int kk = 0; kk < BK; ++kk) {
      float4 a4 = *(const float4*)&as[kk][ty * 4];
      float4 b4 = *(const float4*)&bs[kk][tx * 4];
      float ar[4] = {a4.x, a4.y, a4.z, a4.w};
      float br[4] = {b4.x, b4.y, b4.z, b4.w};
#pragma unroll
      for (int i = 0; i < 4; ++i)
#pragma unroll
        for (int j = 0; j < 4; ++j)
          acc[i][j] = fmaf(ar[i], br[j], acc[i][j]);
    }
    __syncthreads();
  }

  float* outp = part + (size_t)sk * M_ * XDW_;
#pragma unroll
  for (int i = 0; i < 4; ++i) {
    int r = bm + ty * 4 + i;
    int c = bn + tx * 4;
    float4 o = {acc[i][0], acc[i][1], acc[i][2], acc[i][3]};
    *(float4*)(outp + (size_t)r * XDW_ + c) = o;
  }
}

// reduce partials: xdbl[i] = sum_sk part[sk][i]
__global__ __launch_bounds__(256) void reduce_sk(
    const float* __restrict__ part, float* __restrict__ xdbl)
{
  int i = blockIdx.x * 256 + threadIdx.x;
  float s = 0.f;
#pragma unroll
  for (int sk = 0; sk < SK_; ++sk) s += part[(size_t)sk * M_ * XDW_ + i];
  xdbl[i] = s;
}

// ---------------- depthwise causal conv (K=4) + SiLU ----------------
#define LCH 32
__global__ __launch_bounds__(256) void conv_silu_kernel(
    const float* __restrict__ xz, const float* __restrict__ cw,
    const float* __restrict__ cb, float* __restrict__ u)
{
  int d  = blockIdx.x * 256 + threadIdx.x;
  int l0 = blockIdx.y * LCH;
  int b  = blockIdx.z;
  float w0 = cw[d * 4 + 0], w1 = cw[d * 4 + 1];
  float w2 = cw[d * 4 + 2], w3 = cw[d * 4 + 3];
  float bias = cb[d];
  const float* xi = xz + (size_t)(b * L_) * XZW_ + d;
  float x3 = (l0 >= 3) ? xi[(size_t)(l0 - 3) * XZW_] : 0.f;
  float x2 = (l0 >= 2) ? xi[(size_t)(l0 - 2) * XZW_] : 0.f;
  float x1 = (l0 >= 1) ? xi[(size_t)(l0 - 1) * XZW_] : 0.f;
  for (int l = l0; l < l0 + LCH; ++l) {
    float x0 = xi[(size_t)l * XZW_];
    float v = w0 * x3 + w1 * x2 + w2 * x1 + w3 * x0 + bias;
    float uu = v / (1.f + __expf(-v));
    u[((size_t)(b * L_) + l) * DI_ + d] = uu;
    x3 = x2; x2 = x1; x1 = x0;
  }
}

// ---------------- chunked selective scan (4 states/lane, 4 lanes/channel) ----
__global__ __launch_bounds__(256) void scan_p1(
    const float* __restrict__ dlt, const float* __restrict__ u,
    const float* __restrict__ xdbl, const float* __restrict__ A_log,
    float* __restrict__ Pbuf, unsigned short* __restrict__ hend)
{
  int t = threadIdx.x;
  int ng = t & 3, dl = t >> 2;
  int d = blockIdx.x * 64 + dl;
  int b = blockIdx.y;
  int c = blockIdx.z;
  int l0 = c * CLEN_;
  float4 Al = *(const float4*)(A_log + d * NS_ + ng * 4);
  float A0 = -__expf(Al.x), A1 = -__expf(Al.y), A2 = -__expf(Al.z), A3 = -__expf(Al.w);
  float h0 = 0.f, h1 = 0.f, h2 = 0.f, h3 = 0.f, S = 0.f;
  const float* dp = dlt + ((size_t)(b * L_) + l0) * DI_ + d;
  const float* up = u   + ((size_t)(b * L_) + l0) * DI_ + d;
  const float* xp = xdbl + ((size_t)(b * L_) + l0) * XDW_ + DTR_ + ng * 4;
  float dv = dp[0], uv = up[0];
  float4 Bv = *(const float4*)xp;
  for (int l = 0; l < CLEN_; ++l) {
    int ln = (l + 1 < CLEN_) ? l + 1 : l;
    float dv_n = dp[(size_t)ln * DI_];
    float uv_n = up[(size_t)ln * DI_];
    float4 Bv_n = *(const float4*)(xp + (size_t)ln * XDW_);
    float dvu = dv * uv;
    h0 = __expf(dv * A0) * h0 + dvu * Bv.x;
    h1 = __expf(dv * A1) * h1 + dvu * Bv.y;
    h2 = __expf(dv * A2) * h2 + dvu * Bv.z;
    h3 = __expf(dv * A3) * h3 + dvu * Bv.w;
    S += dv;
    dv = dv_n; uv = uv_n; Bv = Bv_n;
  }
  size_t i = ((size_t)((b * CH_ + c) * DI_) + d) * NS_ + ng * 4;
  float4 P; P.x = __expf(S * A0); P.y = __expf(S * A1);
  P.z = __expf(S * A2); P.w = __expf(S * A3);
  u16x4 H; H[0] = f2bf(h0); H[1] = f2bf(h1); H[2] = f2bf(h2); H[3] = f2bf(h3);
  *(float4*)(Pbuf + i) = P;
  *(u16x4*)(hend + i) = H;
}

__global__ __launch_bounds__(256) void scan_p2(
    float* __restrict__ Pbuf, const unsigned short* __restrict__ hend)
{
  int tid = blockIdx.x * 256 + threadIdx.x;   // over B*DI*NS = 65536
  int n = tid & 15;
  int d = (tid >> 4) & (DI_ - 1);
  int b = tid >> 15;
  float h = 0.f;
  for (int c = 0; c < CH_; ++c) {
    size_t i = ((size_t)((b * CH_ + c) * DI_) + d) * NS_ + n;
    float Pv = Pbuf[i];
    float he = bf2f(hend[i]);
    Pbuf[i] = h;
    h = Pv * h + he;
  }
}

__global__ __launch_bounds__(256) void scan_p3(
    const float* __restrict__ dlt, const float* __restrict__ u,
    const float* __restrict__ xdbl, const float* __restrict__ A_log,
    const float* __restrict__ hin, const float* __restrict__ xz,
    const float* __restrict__ Dp, unsigned short* __restrict__ yb)
{
  int t = threadIdx.x;
  int ng = t & 3, dl = t >> 2;
  int d = blockIdx.x * 64 + dl;
  int b = blockIdx.y;
  int c = blockIdx.z;
  int l0 = c * CLEN_;
  float4 Al = *(const float4*)(A_log + d * NS_ + ng * 4);
  float A0 = -__expf(Al.x), A1 = -__expf(Al.y), A2 = -__expf(Al.z), A3 = -__expf(Al.w);
  size_t i0 = ((size_t)((b * CH_ + c) * DI_) + d) * NS_ + ng * 4;
  float4 hv = *(const float4*)(hin + i0);
  float h0 = hv.x, h1 = hv.y, h2 = hv.z, h3 = hv.w;
  float Dd = Dp[d];
  const float* dp = dlt + ((size_t)(b * L_) + l0) * DI_ + d;
  const float* up = u   + ((size_t)(b * L_) + l0) * DI_ + d;
  const float* xp = xdbl + ((size_t)(b * L_) + l0) * XDW_ + DTR_ + ng * 4;
  const float* zp = xz + ((size_t)(b * L_) + l0) * XZW_ + DI_ + d;
  unsigned short* yp = yb + ((size_t)(b * L_) + l0) * DI_ + d;
  float dv = dp[0], uv = up[0];
  float4 Bv = *(const float4*)xp;
  float4 Cv = *(const float4*)(xp + NS_);
  for (int l = 0; l < CLEN_; ++l) {
    int ln = (l + 1 < CLEN_) ? l + 1 : l;
    float dv_n = dp[(size_t)ln * DI_];
    float uv_n = up[(size_t)ln * DI_];
    float4 Bv_n = *(const float4*)(xp + (size_t)ln * XDW_);
    float4 Cv_n = *(const float4*)(xp + (size_t)ln * XDW_ + NS_);
    float dvu = dv * uv;
    h0 = __expf(dv * A0) * h0 + dvu * Bv.x;
    h1 = __expf(dv * A1) * h1 + dvu * Bv.y;
    h2 = __expf(dv * A2) * h2 + dvu * Bv.z;
    h3 = __expf(dv * A3) * h3 + dvu * Bv.w;
    float py = h0 * Cv.x + h1 * Cv.y + h2 * Cv.z + h3 * Cv.w;
    py += __shfl_xor(py, 1);
    py += __shfl_xor(py, 2);
    if (ng == 0) {
      float z = zp[(size_t)l * XZW_];
      float zs = z / (1.f + __expf(-z));
      yp[(size_t)l * DI_] = f2bf((py + uv * Dd) * zs);
    }
    dv = dv_n; uv = uv_n; Bv = Bv_n; Cv = Cv_n;
  }
}

extern "C" void kernel_launch(void* const* d_in, const int* in_sizes, int n_in,
                              void* d_out, int out_size, void* d_ws, size_t ws_size,
                              hipStream_t stream)
{
  const float* x         = (const float*)d_in[0];
  const float* ln_g      = (const float*)d_in[1];
  const float* ln_b      = (const float*)d_in[2];
  const float* in_proj_w = (const float*)d_in[3];
  const float* conv_w    = (const float*)d_in[4];
  const float* conv_b    = (const float*)d_in[5];
  const float* x_proj_w  = (const float*)d_in[6];
  const float* dt_proj_w = (const float*)d_in[7];
  const float* dt_proj_b = (const float*)d_in[8];
  const float* A_log     = (const float*)d_in[9];
  const float* Dp        = (const float*)d_in[10];
  const float* out_proj_w= (const float*)d_in[11];
  float* out = (float*)d_out;

  float* ws = (float*)d_ws;
  float* xz   = ws;                  // 2048*4096          = 8,388,608 f
  float* u    = ws + 8388608;        // 2048*2048          = 4,194,304 f
  float* xdbl = ws + 12582912;       // 2048*128           =   262,144 f
  float* dlt  = ws + 12845056;       // 2048*2048          = 4,194,304 f
  unsigned short* xnb   = (unsigned short*)(ws + 17039360); // 1,048,576 f region
  float* winb_f = ws + 18087936;     // 2,097,152 f: winb bf16 / sk-partials / Pbuf
  unsigned short* winb  = (unsigned short*)winb_f;
  unsigned short* woutb = (unsigned short*)(ws + 20185088); // 1,048,576 f
  unsigned short* yb    = (unsigned short*)(ws + 21233664); // 1,048,576 f
  // scan boundary buffers (aliases of dead regions):
  float* Pbuf = winb_f;                       // 2*32*2048*16 = 2,097,152 f
  unsigned short* hendb = xnb;                // 2,097,152 bf16 (xnb region, dead)
  // total 23,330,816 floats = 93.3 MB

  // 1. LayerNorm -> bf16
  ln_kernel<<<M_, 256, 0, stream>>>(x, ln_g, ln_b, xnb);

  // 2. weight conversions fp32 -> bf16
  f2bf_kernel<<<4096, 256, 0, stream>>>((const float4*)in_proj_w, (u16x4*)winb);
  f2bf_kernel<<<2048, 256, 0, stream>>>((const float4*)out_proj_w, (u16x4*)woutb);

  // 3. in_proj (MFMA, dbuf): xz = xn @ in_proj_w^T   (grid 32x16 = 512 blocks)
  gemm_mfma<0, 128><<<dim3(XZW_ / 128, M_ / 128), 256, 0, stream>>>(
      (const short*)xnb, DM_, (const short*)winb, DM_, xz, XZW_, DM_, nullptr, 0);

  // 4. conv + silu -> u
  conv_silu_kernel<<<dim3(DI_ / 256, L_ / LCH, B_), 256, 0, stream>>>(
      xz, conv_w, conv_b, u);

  // 5. x_proj split-K (partials into winb region, dead after in_proj) + reduce
  gemm_nt_sk<<<dim3(XDW_ / BN, M_ / BM, SK_), 256, 0, stream>>>(
      u, DI_, x_proj_w, DI_, winb_f, 96);
  reduce_sk<<<(M_ * XDW_) / 256, 256, 0, stream>>>(winb_f, xdbl);

  // 6. dt_proj + softplus
  gemm_nt<<<dim3(DI_ / BN, M_ / BM), 256, 0, stream>>>(
      xdbl, XDW_, dt_proj_w, DTR_, dlt, DI_, M_, DI_, DTR_, 1, dt_proj_b);

  // 7. chunked scan (Pbuf aliases winb; hend bf16 aliases xnb — both dead now)
  scan_p1<<<dim3(DI_ / 64, B_, CH_), 256, 0, stream>>>(dlt, u, xdbl, A_log, Pbuf, hendb);
  scan_p2<<<(B_ * DI_ * NS_) / 256, 256, 0, stream>>>(Pbuf, hendb);
  scan_p3<<<dim3(DI_ / 64, B_, CH_), 256, 0, stream>>>(
      dlt, u, xdbl, A_log, Pbuf, xz, Dp, yb);

  // 8. out_proj (MFMA, dbuf, TN=64): grid (16,16) = 256 blocks — full CU coverage
  gemm_mfma<2, 64><<<dim3(DM_ / 64, M_ / 128), 256, 0, stream>>>(
      (const short*)yb, DI_, (const short*)woutb, DI_, out, DM_, DI_, x, DM_);
}

// Round 12
// 271.510 us; speedup vs baseline: 4.0783x; 1.0066x over previous
//
#include <hip/hip_runtime.h>
#include <hip/hip_bf16.h>
#include <math.h>

#define B_   2
#define L_   1024
#define DM_  1024
#define DI_  2048
#define NS_  16
#define DTR_ 64
#define M_   (B_ * L_)          // 2048 rows
#define XZW_ (2 * DI_)          // 4096
#define XDW_ 128                // padded x_proj output width (dt|B|C|pad)
#define CH_  32                 // scan chunks
#define CLEN_ (L_ / CH_)        // 32
#define SK_  8                  // x_proj split-K chunks
#define KCH_ (DI_ / SK_)        // 256

typedef __attribute__((ext_vector_type(8))) short bf16x8;
typedef __attribute__((ext_vector_type(4))) float f32x4;
typedef __attribute__((ext_vector_type(4))) unsigned short u16x4;

static __device__ __forceinline__ unsigned short f2bf(float f) {
  __hip_bfloat16 h = __float2bfloat16(f);
  return *reinterpret_cast<unsigned short*>(&h);
}
static __device__ __forceinline__ float bf2f(unsigned short u) {
  unsigned int x = ((unsigned int)u) << 16;
  float f;
  __builtin_memcpy(&f, &x, 4);
  return f;
}

// ---------------- LayerNorm -> bf16 ----------------
__global__ __launch_bounds__(256) void ln_kernel(
    const float* __restrict__ x, const float* __restrict__ g,
    const float* __restrict__ b, unsigned short* __restrict__ xnb)
{
  int r = blockIdx.x;
  int t = threadIdx.x;
  const float4* xr = (const float4*)(x + (size_t)r * DM_);
  float4 v = xr[t];
  float s  = v.x + v.y + v.z + v.w;
  float ss = v.x * v.x + v.y * v.y + v.z * v.z + v.w * v.w;
  for (int m = 32; m >= 1; m >>= 1) {
    s  += __shfl_down(s, m);
    ss += __shfl_down(ss, m);
  }
  __shared__ float sb[4], ssb[4];
  int w = t >> 6, lane = t & 63;
  if (lane == 0) { sb[w] = s; ssb[w] = ss; }
  __syncthreads();
  s  = sb[0] + sb[1] + sb[2] + sb[3];
  ss = ssb[0] + ssb[1] + ssb[2] + ssb[3];
  float mu  = s * (1.f / DM_);
  float var = ss * (1.f / DM_) - mu * mu;
  float rs  = rsqrtf(var + 1e-5f);
  float4 gv = ((const float4*)g)[t];
  float4 bv = ((const float4*)b)[t];
  u16x4 o;
  o[0] = f2bf((v.x - mu) * rs * gv.x + bv.x);
  o[1] = f2bf((v.y - mu) * rs * gv.y + bv.y);
  o[2] = f2bf((v.z - mu) * rs * gv.z + bv.z);
  o[3] = f2bf((v.w - mu) * rs * gv.w + bv.w);
  ((u16x4*)xnb)[r * 256 + t] = o;
}

// ---------------- fp32 -> bf16 bulk convert ----------------
__global__ __launch_bounds__(256) void f2bf_kernel(
    const float4* __restrict__ in, u16x4* __restrict__ outp)
{
  int i = blockIdx.x * 256 + threadIdx.x;
  float4 v = in[i];
  u16x4 o;
  o[0] = f2bf(v.x); o[1] = f2bf(v.y); o[2] = f2bf(v.z); o[3] = f2bf(v.w);
  outp[i] = o;
}

// ---------------- bf16 MFMA GEMM NT with 2-phase double-buffered prefetch ----
// TM=128 fixed; TN in {128, 64}. 4 waves.
// MODE 0: f32 store ; MODE 1: f32 softplus(acc+bias[col]) ; MODE 2: f32 acc+res ;
// MODE 3: bf16 store.
template<int MODE, int TN>
__global__ __launch_bounds__(256) void gemm_mfma(
    const short* __restrict__ A, int lda,
    const short* __restrict__ Bw, int ldb,
    void* __restrict__ Cv, int ldc, int Kdim,
    const float* __restrict__ res, int ldres,
    const float* __restrict__ bias)
{
  constexpr int MREP = (TN == 128) ? 4 : 2;
  constexpr int NREP = 4;
  constexpr int WM   = (TN == 128) ? 64 : 32;
  __shared__ __align__(16) short As[2][128 * 64];
  __shared__ __align__(16) short Bs[2][TN * 64];
  const int bm = blockIdx.y * 128, bn = blockIdx.x * TN;
  const int t = threadIdx.x, wid = t >> 6, lane = t & 63;
  const int wr = (TN == 128) ? (wid >> 1) : wid;
  const int wc = (TN == 128) ? (wid & 1) : 0;

  f32x4 acc[MREP][NREP];
#pragma unroll
  for (int i = 0; i < MREP; ++i)
#pragma unroll
    for (int j = 0; j < NREP; ++j) acc[i][j] = (f32x4){0.f, 0.f, 0.f, 0.f};

  const int srow = wid * 8 + (lane >> 3);
  const int sc   = lane & 7;
  const int r16 = lane & 15, khalf = lane >> 4;

  auto STAGE = [&](int buf, int k0) {
#pragma unroll
    for (int q = 0; q < 4; ++q) {
      int row = q * 32 + srow;
      int csw = sc ^ (row & 7);
      const short* gA = A + (size_t)(bm + row) * lda + k0 + csw * 8;
      __builtin_amdgcn_global_load_lds(
          (const __attribute__((address_space(1))) void*)gA,
          (__attribute__((address_space(3))) void*)(&As[buf][q * 2048 + wid * 512]),
          16, 0, 0);
    }
#pragma unroll
    for (int q = 0; q < TN / 32; ++q) {
      int row = q * 32 + srow;
      int csw = sc ^ (row & 7);
      const short* gB = Bw + (size_t)(bn + row) * ldb + k0 + csw * 8;
      __builtin_amdgcn_global_load_lds(
          (const __attribute__((address_space(1))) void*)gB,
          (__attribute__((address_space(3))) void*)(&Bs[buf][q * 2048 + wid * 512]),
          16, 0, 0);
    }
  };

  const int nt = Kdim >> 6;
  STAGE(0, 0);
  int cur = 0;
  for (int ti = 0; ti < nt; ++ti) {
    __syncthreads();
    if (ti + 1 < nt) STAGE(cur ^ 1, (ti + 1) << 6);

    bf16x8 af[MREP][2], bfr[NREP][2];
#pragma unroll
    for (int m = 0; m < MREP; ++m)
#pragma unroll
      for (int kk = 0; kk < 2; ++kk) {
        int c16 = kk * 4 + khalf;
        int rowa = wr * WM + m * 16 + r16;
        af[m][kk] = *(const bf16x8*)(&As[cur][rowa * 64 + ((c16 ^ (rowa & 7)) << 3)]);
      }
#pragma unroll
    for (int nn = 0; nn < NREP; ++nn)
#pragma unroll
      for (int kk = 0; kk < 2; ++kk) {
        int c16 = kk * 4 + khalf;
        int rowb = wc * 64 + nn * 16 + r16;
        bfr[nn][kk] = *(const bf16x8*)(&Bs[cur][rowb * 64 + ((c16 ^ (rowb & 7)) << 3)]);
      }
#pragma unroll
    for (int kk = 0; kk < 2; ++kk)
#pragma unroll
      for (int m = 0; m < MREP; ++m)
#pragma unroll
        for (int nn = 0; nn < NREP; ++nn)
          acc[m][nn] = __builtin_amdgcn_mfma_f32_16x16x32_bf16(
              af[m][kk], bfr[nn][kk], acc[m][nn], 0, 0, 0);
    cur ^= 1;
  }

  const int rgrp = lane >> 4;
#pragma unroll
  for (int m = 0; m < MREP; ++m)
#pragma unroll
    for (int nn = 0; nn < NREP; ++nn) {
      int col = bn + wc * 64 + nn * 16 + r16;
#pragma unroll
      for (int rg = 0; rg < 4; ++rg) {
        int row = bm + wr * WM + m * 16 + rgrp * 4 + rg;
        float v = acc[m][nn][rg];
        if (MODE == 1) {
          v += bias[col];
          v = (v > 20.f) ? v : log1pf(expf(v));
        }
        if (MODE == 2) v += res[(size_t)row * ldres + col];
        if (MODE == 3)
          ((unsigned short*)Cv)[(size_t)row * ldc + col] = f2bf(v);
        else
          ((float*)Cv)[(size_t)row * ldc + col] = v;
      }
    }
}

// ---------------- split-K fp32 NT GEMM for x_proj ----------------
#define BM 64
#define BN 64
#define BK 32
#define PADR 68

__global__ __launch_bounds__(256) void gemm_nt_sk(
    const float* __restrict__ A, int lda,
    const float* __restrict__ Bw, int ldb,
    float* __restrict__ part, int Ncols)
{
  __shared__ float as[BK][PADR];
  __shared__ float bs[BK][PADR];
  int bm = blockIdx.y * BM;
  int bn = blockIdx.x * BN;
  int sk = blockIdx.z;
  int t  = threadIdx.x;
  int tx = t & 15, ty = t >> 4;

  float acc[4][4] = {};

  int m0 = t >> 3;
  int kq = t & 7;
  const float4 z4 = {0.f, 0.f, 0.f, 0.f};

  for (int k0 = sk * KCH_; k0 < (sk + 1) * KCH_; k0 += BK) {
    float4 a0 = *(const float4*)(A + (size_t)(bm + m0) * lda + k0 + kq * 4);
    float4 a1 = *(const float4*)(A + (size_t)(bm + m0 + 32) * lda + k0 + kq * 4);
    float4 b0 = (bn + m0 < Ncols)
        ? *(const float4*)(Bw + (size_t)(bn + m0) * ldb + k0 + kq * 4) : z4;
    float4 b1 = (bn + m0 + 32 < Ncols)
        ? *(const float4*)(Bw + (size_t)(bn + m0 + 32) * ldb + k0 + kq * 4) : z4;
    as[kq * 4 + 0][m0] = a0.x;  as[kq * 4 + 1][m0] = a0.y;
    as[kq * 4 + 2][m0] = a0.z;  as[kq * 4 + 3][m0] = a0.w;
    as[kq * 4 + 0][m0 + 32] = a1.x;  as[kq * 4 + 1][m0 + 32] = a1.y;
    as[kq * 4 + 2][m0 + 32] = a1.z;  as[kq * 4 + 3][m0 + 32] = a1.w;
    bs[kq * 4 + 0][m0] = b0.x;  bs[kq * 4 + 1][m0] = b0.y;
    bs[kq * 4 + 2][m0] = b0.z;  bs[kq * 4 + 3][m0] = b0.w;
    bs[kq * 4 + 0][m0 + 32] = b1.x;  bs[kq * 4 + 1][m0 + 32] = b1.y;
    bs[kq * 4 + 2][m0 + 32] = b1.z;  bs[kq * 4 + 3][m0 + 32] = b1.w;
    __syncthreads();

#pragma unroll
    for (int kk = 0; kk < BK; ++kk) {
      float4 a4 = *(const float4*)&as[kk][ty * 4];
      float4 b4 = *(const float4*)&bs[kk][tx * 4];
      float ar[4] = {a4.x, a4.y, a4.z, a4.w};
      float br[4] = {b4.x, b4.y, b4.z, b4.w};
#pragma unroll
      for (int i = 0; i < 4; ++i)
#pragma unroll
        for (int j = 0; j < 4; ++j)
          acc[i][j] = fmaf(ar[i], br[j], acc[i][j]);
    }
    __syncthreads();
  }

  float* outp = part + (size_t)sk * M_ * XDW_;
#pragma unroll
  for (int i = 0; i < 4; ++i) {
    int r = bm + ty * 4 + i;
    int c = bn + tx * 4;
    float4 o = {acc[i][0], acc[i][1], acc[i][2], acc[i][3]};
    *(float4*)(outp + (size_t)r * XDW_ + c) = o;
  }
}

// reduce partials: xdbl[i] = sum_sk part[sk][i]; dt slice (cols 0..63) also -> bf16
__global__ __launch_bounds__(256) void reduce_sk(
    const float* __restrict__ part, float* __restrict__ xdbl,
    unsigned short* __restrict__ xdtb)
{
  int i = blockIdx.x * 256 + threadIdx.x;
  float s = 0.f;
#pragma unroll
  for (int sk = 0; sk < SK_; ++sk) s += part[(size_t)sk * M_ * XDW_ + i];
  xdbl[i] = s;
  int col = i & (XDW_ - 1);
  if (col < DTR_) xdtb[(size_t)(i >> 7) * DTR_ + col] = f2bf(s);
}

// ---------------- depthwise causal conv (K=4, bf16 in) + SiLU ----------------
#define LCH 8
__global__ __launch_bounds__(256) void conv_silu_kernel(
    const unsigned short* __restrict__ xzb, const float* __restrict__ cw,
    const float* __restrict__ cb, float* __restrict__ u)
{
  int d  = blockIdx.x * 256 + threadIdx.x;
  int l0 = blockIdx.y * LCH;
  int b  = blockIdx.z;
  float w0 = cw[d * 4 + 0], w1 = cw[d * 4 + 1];
  float w2 = cw[d * 4 + 2], w3 = cw[d * 4 + 3];
  float bias = cb[d];
  const unsigned short* xi = xzb + (size_t)(b * L_) * XZW_ + d;
  float x3 = (l0 >= 3) ? bf2f(xi[(size_t)(l0 - 3) * XZW_]) : 0.f;
  float x2 = (l0 >= 2) ? bf2f(xi[(size_t)(l0 - 2) * XZW_]) : 0.f;
  float x1 = (l0 >= 1) ? bf2f(xi[(size_t)(l0 - 1) * XZW_]) : 0.f;
#pragma unroll
  for (int l = l0; l < l0 + LCH; ++l) {
    float x0 = bf2f(xi[(size_t)l * XZW_]);
    float v = w0 * x3 + w1 * x2 + w2 * x1 + w3 * x0 + bias;
    float uu = v / (1.f + __expf(-v));
    u[((size_t)(b * L_) + l) * DI_ + d] = uu;
    x3 = x2; x2 = x1; x1 = x0;
  }
}

// ---------------- chunked selective scan (4 states/lane, 4 lanes/channel) ----
__global__ __launch_bounds__(256) void scan_p1(
    const float* __restrict__ dlt, const float* __restrict__ u,
    const float* __restrict__ xdbl, const float* __restrict__ A_log,
    float* __restrict__ Pbuf, unsigned short* __restrict__ hend)
{
  int t = threadIdx.x;
  int ng = t & 3, dl = t >> 2;
  int d = blockIdx.x * 64 + dl;
  int b = blockIdx.y;
  int c = blockIdx.z;
  int l0 = c * CLEN_;
  float4 Al = *(const float4*)(A_log + d * NS_ + ng * 4);
  float A0 = -__expf(Al.x), A1 = -__expf(Al.y), A2 = -__expf(Al.z), A3 = -__expf(Al.w);
  float h0 = 0.f, h1 = 0.f, h2 = 0.f, h3 = 0.f, S = 0.f;
  const float* dp = dlt + ((size_t)(b * L_) + l0) * DI_ + d;
  const float* up = u   + ((size_t)(b * L_) + l0) * DI_ + d;
  const float* xp = xdbl + ((size_t)(b * L_) + l0) * XDW_ + DTR_ + ng * 4;
  float dv = dp[0], uv = up[0];
  float4 Bv = *(const float4*)xp;
  for (int l = 0; l < CLEN_; ++l) {
    int ln = (l + 1 < CLEN_) ? l + 1 : l;
    float dv_n = dp[(size_t)ln * DI_];
    float uv_n = up[(size_t)ln * DI_];
    float4 Bv_n = *(const float4*)(xp + (size_t)ln * XDW_);
    float dvu = dv * uv;
    h0 = __expf(dv * A0) * h0 + dvu * Bv.x;
    h1 = __expf(dv * A1) * h1 + dvu * Bv.y;
    h2 = __expf(dv * A2) * h2 + dvu * Bv.z;
    h3 = __expf(dv * A3) * h3 + dvu * Bv.w;
    S += dv;
    dv = dv_n; uv = uv_n; Bv = Bv_n;
  }
  size_t i = ((size_t)((b * CH_ + c) * DI_) + d) * NS_ + ng * 4;
  float4 P; P.x = __expf(S * A0); P.y = __expf(S * A1);
  P.z = __expf(S * A2); P.w = __expf(S * A3);
  u16x4 H; H[0] = f2bf(h0); H[1] = f2bf(h1); H[2] = f2bf(h2); H[3] = f2bf(h3);
  *(float4*)(Pbuf + i) = P;
  *(u16x4*)(hend + i) = H;
}

__global__ __launch_bounds__(256) void scan_p2(
    float* __restrict__ Pbuf, const unsigned short* __restrict__ hend)
{
  int tid = blockIdx.x * 256 + threadIdx.x;   // over B*DI*NS = 65536
  int n = tid & 15;
  int d = (tid >> 4) & (DI_ - 1);
  int b = tid >> 15;
  float h = 0.f;
  for (int c = 0; c < CH_; ++c) {
    size_t i = ((size_t)((b * CH_ + c) * DI_) + d) * NS_ + n;
    float Pv = Pbuf[i];
    float he = bf2f(hend[i]);
    Pbuf[i] = h;
    h = Pv * h + he;
  }
}

__global__ __launch_bounds__(256) void scan_p3(
    const float* __restrict__ dlt, const float* __restrict__ u,
    const float* __restrict__ xdbl, const float* __restrict__ A_log,
    const float* __restrict__ hin, const unsigned short* __restrict__ xzb,
    const float* __restrict__ Dp, unsigned short* __restrict__ yb)
{
  int t = threadIdx.x;
  int ng = t & 3, dl = t >> 2;
  int d = blockIdx.x * 64 + dl;
  int b = blockIdx.y;
  int c = blockIdx.z;
  int l0 = c * CLEN_;
  float4 Al = *(const float4*)(A_log + d * NS_ + ng * 4);
  float A0 = -__expf(Al.x), A1 = -__expf(Al.y), A2 = -__expf(Al.z), A3 = -__expf(Al.w);
  size_t i0 = ((size_t)((b * CH_ + c) * DI_) + d) * NS_ + ng * 4;
  float4 hv = *(const float4*)(hin + i0);
  float h0 = hv.x, h1 = hv.y, h2 = hv.z, h3 = hv.w;
  float Dd = Dp[d];
  const float* dp = dlt + ((size_t)(b * L_) + l0) * DI_ + d;
  const float* up = u   + ((size_t)(b * L_) + l0) * DI_ + d;
  const float* xp = xdbl + ((size_t)(b * L_) + l0) * XDW_ + DTR_ + ng * 4;
  const unsigned short* zp = xzb + ((size_t)(b * L_) + l0) * XZW_ + DI_ + d;
  unsigned short* yp = yb + ((size_t)(b * L_) + l0) * DI_ + d;
  float dv = dp[0], uv = up[0];
  float4 Bv = *(const float4*)xp;
  float4 Cv = *(const float4*)(xp + NS_);
  for (int l = 0; l < CLEN_; ++l) {
    int ln = (l + 1 < CLEN_) ? l + 1 : l;
    float dv_n = dp[(size_t)ln * DI_];
    float uv_n = up[(size_t)ln * DI_];
    float4 Bv_n = *(const float4*)(xp + (size_t)ln * XDW_);
    float4 Cv_n = *(const float4*)(xp + (size_t)ln * XDW_ + NS_);
    float dvu = dv * uv;
    h0 = __expf(dv * A0) * h0 + dvu * Bv.x;
    h1 = __expf(dv * A1) * h1 + dvu * Bv.y;
    h2 = __expf(dv * A2) * h2 + dvu * Bv.z;
    h3 = __expf(dv * A3) * h3 + dvu * Bv.w;
    float py = h0 * Cv.x + h1 * Cv.y + h2 * Cv.z + h3 * Cv.w;
    py += __shfl_xor(py, 1);
    py += __shfl_xor(py, 2);
    if (ng == 0) {
      float z = bf2f(zp[(size_t)l * XZW_]);
      float zs = z / (1.f + __expf(-z));
      yp[(size_t)l * DI_] = f2bf((py + uv * Dd) * zs);
    }
    dv = dv_n; uv = uv_n; Bv = Bv_n; Cv = Cv_n;
  }
}

extern "C" void kernel_launch(void* const* d_in, const int* in_sizes, int n_in,
                              void* d_out, int out_size, void* d_ws, size_t ws_size,
                              hipStream_t stream)
{
  const float* x         = (const float*)d_in[0];
  const float* ln_g      = (const float*)d_in[1];
  const float* ln_b      = (const float*)d_in[2];
  const float* in_proj_w = (const float*)d_in[3];
  const float* conv_w    = (const float*)d_in[4];
  const float* conv_b    = (const float*)d_in[5];
  const float* x_proj_w  = (const float*)d_in[6];
  const float* dt_proj_w = (const float*)d_in[7];
  const float* dt_proj_b = (const float*)d_in[8];
  const float* A_log     = (const float*)d_in[9];
  const float* Dp        = (const float*)d_in[10];
  const float* out_proj_w= (const float*)d_in[11];
  float* out = (float*)d_out;

  float* ws = (float*)d_ws;
  unsigned short* xzb = (unsigned short*)ws;            // 2048*4096 bf16 (4,194,304 f)
  float* u    = ws + 4194304;        // 4,194,304 f
  float* xdbl = ws + 8388608;        //   262,144 f
  float* dlt  = ws + 8650752;        // 4,194,304 f
  unsigned short* xdtb = (unsigned short*)(ws + 12845056); // 2048*64 bf16 (65,536 f)
  unsigned short* dtwb = (unsigned short*)(ws + 12910592); // 2048*64 bf16 (65,536 f)
  unsigned short* xnb  = (unsigned short*)(ws + 12976128); // 1,048,576 f region
  float* winb_f = ws + 14024704;     // 2,097,152 f: winb bf16 / sk-partials / Pbuf
  unsigned short* winb  = (unsigned short*)winb_f;
  unsigned short* woutb = (unsigned short*)(ws + 16121856); // 1,048,576 f
  unsigned short* yb    = (unsigned short*)(ws + 17170432); // 1,048,576 f
  float* Pbuf = winb_f;                       // 2*32*2048*16 = 2,097,152 f
  unsigned short* hendb = xnb;                // 2,097,152 bf16 (xnb region, dead)
  // total 18,219,008 floats = 72.9 MB

  // 1. LayerNorm -> bf16
  ln_kernel<<<M_, 256, 0, stream>>>(x, ln_g, ln_b, xnb);

  // 2. weight conversions fp32 -> bf16
  f2bf_kernel<<<4096, 256, 0, stream>>>((const float4*)in_proj_w, (u16x4*)winb);
  f2bf_kernel<<<2048, 256, 0, stream>>>((const float4*)out_proj_w, (u16x4*)woutb);
  f2bf_kernel<<<128, 256, 0, stream>>>((const float4*)dt_proj_w, (u16x4*)dtwb);

  // 3. in_proj (MFMA, dbuf, bf16 out): xzb = xn @ in_proj_w^T
  gemm_mfma<3, 128><<<dim3(XZW_ / 128, M_ / 128), 256, 0, stream>>>(
      (const short*)xnb, DM_, (const short*)winb, DM_, xzb, XZW_, DM_,
      nullptr, 0, nullptr);

  // 4. conv + silu -> u  (grid 2048 blocks)
  conv_silu_kernel<<<dim3(DI_ / 256, L_ / LCH, B_), 256, 0, stream>>>(
      xzb, conv_w, conv_b, u);

  // 5. x_proj split-K + reduce (also emits bf16 dt slice)
  gemm_nt_sk<<<dim3(XDW_ / BN, M_ / BM, SK_), 256, 0, stream>>>(
      u, DI_, x_proj_w, DI_, winb_f, 96);
  reduce_sk<<<(M_ * XDW_) / 256, 256, 0, stream>>>(winb_f, xdbl, xdtb);

  // 6. dt_proj (MFMA, K=64, fused bias+softplus): dlt = softplus(xdt @ dtw^T + b)
  gemm_mfma<1, 128><<<dim3(DI_ / 128, M_ / 128), 256, 0, stream>>>(
      (const short*)xdtb, DTR_, (const short*)dtwb, DTR_, dlt, DI_, DTR_,
      nullptr, 0, dt_proj_b);

  // 7. chunked scan (Pbuf aliases winb; hend bf16 aliases xnb — both dead now)
  scan_p1<<<dim3(DI_ / 64, B_, CH_), 256, 0, stream>>>(dlt, u, xdbl, A_log, Pbuf, hendb);
  scan_p2<<<(B_ * DI_ * NS_) / 256, 256, 0, stream>>>(Pbuf, hendb);
  scan_p3<<<dim3(DI_ / 64, B_, CH_), 256, 0, stream>>>(
      dlt, u, xdbl, A_log, Pbuf, xzb, Dp, yb);

  // 8. out_proj (MFMA, dbuf, TN=64) + residual
  gemm_mfma<2, 64><<<dim3(DM_ / 64, M_ / 128), 256, 0, stream>>>(
      (const short*)yb, DI_, (const short*)woutb, DI_, out, DM_, DI_, x, DM_, nullptr);
}

// Round 14
// 270.109 us; speedup vs baseline: 4.0995x; 1.0052x over previous
//
#include <hip/hip_runtime.h>
#include <hip/hip_bf16.h>
#include <math.h>

#define B_   2
#define L_   1024
#define DM_  1024
#define DI_  2048
#define NS_  16
#define DTR_ 64
#define M_   (B_ * L_)          // 2048 rows
#define XZW_ (2 * DI_)          // 4096
#define XDW_ 128                // padded x_proj output width (dt|B|C|pad)
#define CH_  64                 // scan chunks
#define CLEN_ (L_ / CH_)        // 16
#define SK_  8                  // x_proj split-K chunks
#define KCH_ (DI_ / SK_)        // 256

typedef __attribute__((ext_vector_type(8))) short bf16x8;
typedef __attribute__((ext_vector_type(4))) float f32x4;
typedef __attribute__((ext_vector_type(4))) unsigned short u16x4;

static __device__ __forceinline__ unsigned short f2bf(float f) {
  __hip_bfloat16 h = __float2bfloat16(f);
  return *reinterpret_cast<unsigned short*>(&h);
}
static __device__ __forceinline__ float bf2f(unsigned short u) {
  unsigned int x = ((unsigned int)u) << 16;
  float f;
  __builtin_memcpy(&f, &x, 4);
  return f;
}

// ---------------- LayerNorm -> bf16 ----------------
__global__ __launch_bounds__(256) void ln_kernel(
    const float* __restrict__ x, const float* __restrict__ g,
    const float* __restrict__ b, unsigned short* __restrict__ xnb)
{
  int r = blockIdx.x;
  int t = threadIdx.x;
  const float4* xr = (const float4*)(x + (size_t)r * DM_);
  float4 v = xr[t];
  float s  = v.x + v.y + v.z + v.w;
  float ss = v.x * v.x + v.y * v.y + v.z * v.z + v.w * v.w;
  for (int m = 32; m >= 1; m >>= 1) {
    s  += __shfl_down(s, m);
    ss += __shfl_down(ss, m);
  }
  __shared__ float sb[4], ssb[4];
  int w = t >> 6, lane = t & 63;
  if (lane == 0) { sb[w] = s; ssb[w] = ss; }
  __syncthreads();
  s  = sb[0] + sb[1] + sb[2] + sb[3];
  ss = ssb[0] + ssb[1] + ssb[2] + ssb[3];
  float mu  = s * (1.f / DM_);
  float var = ss * (1.f / DM_) - mu * mu;
  float rs  = rsqrtf(var + 1e-5f);
  float4 gv = ((const float4*)g)[t];
  float4 bv = ((const float4*)b)[t];
  u16x4 o;
  o[0] = f2bf((v.x - mu) * rs * gv.x + bv.x);
  o[1] = f2bf((v.y - mu) * rs * gv.y + bv.y);
  o[2] = f2bf((v.z - mu) * rs * gv.z + bv.z);
  o[3] = f2bf((v.w - mu) * rs * gv.w + bv.w);
  ((u16x4*)xnb)[r * 256 + t] = o;
}

// ---------------- fused fp32 -> bf16 convert of 3 weight tensors ----------------
// ranges in float4 units: [0,n1) -> w1/o1 ; [n1,n1+n2) -> w2/o2 ; rest -> w3/o3
__global__ __launch_bounds__(256) void f2bf3_kernel(
    const float4* __restrict__ w1, u16x4* __restrict__ o1, int n1,
    const float4* __restrict__ w2, u16x4* __restrict__ o2, int n2,
    const float4* __restrict__ w3, u16x4* __restrict__ o3, int n3)
{
  int i = blockIdx.x * 256 + threadIdx.x;
  const float4* src; u16x4* dst; int j;
  if (i < n1)            { src = w1; dst = o1; j = i; }
  else if (i < n1 + n2)  { src = w2; dst = o2; j = i - n1; }
  else if (i < n1 + n2 + n3) { src = w3; dst = o3; j = i - n1 - n2; }
  else return;
  float4 v = src[j];
  u16x4 o;
  o[0] = f2bf(v.x); o[1] = f2bf(v.y); o[2] = f2bf(v.z); o[3] = f2bf(v.w);
  dst[j] = o;
}

// ---------------- bf16 MFMA GEMM NT with 2-phase double-buffered prefetch ----
// TM=128 fixed; TN in {128, 64}. 4 waves.
// MODE 0: f32 store ; MODE 2: f32 acc+res ; MODE 3: bf16 store ;
// MODE 4: bf16 softplus(acc+bias[col]).
template<int MODE, int TN>
__global__ __launch_bounds__(256) void gemm_mfma(
    const short* __restrict__ A, int lda,
    const short* __restrict__ Bw, int ldb,
    void* __restrict__ Cv, int ldc, int Kdim,
    const float* __restrict__ res, int ldres,
    const float* __restrict__ bias)
{
  constexpr int MREP = (TN == 128) ? 4 : 2;
  constexpr int NREP = 4;
  constexpr int WM   = (TN == 128) ? 64 : 32;
  __shared__ __align__(16) short As[2][128 * 64];
  __shared__ __align__(16) short Bs[2][TN * 64];
  const int bm = blockIdx.y * 128, bn = blockIdx.x * TN;
  const int t = threadIdx.x, wid = t >> 6, lane = t & 63;
  const int wr = (TN == 128) ? (wid >> 1) : wid;
  const int wc = (TN == 128) ? (wid & 1) : 0;

  f32x4 acc[MREP][NREP];
#pragma unroll
  for (int i = 0; i < MREP; ++i)
#pragma unroll
    for (int j = 0; j < NREP; ++j) acc[i][j] = (f32x4){0.f, 0.f, 0.f, 0.f};

  const int srow = wid * 8 + (lane >> 3);
  const int sc   = lane & 7;
  const int r16 = lane & 15, khalf = lane >> 4;

  auto STAGE = [&](int buf, int k0) {
#pragma unroll
    for (int q = 0; q < 4; ++q) {
      int row = q * 32 + srow;
      int csw = sc ^ (row & 7);
      const short* gA = A + (size_t)(bm + row) * lda + k0 + csw * 8;
      __builtin_amdgcn_global_load_lds(
          (const __attribute__((address_space(1))) void*)gA,
          (__attribute__((address_space(3))) void*)(&As[buf][q * 2048 + wid * 512]),
          16, 0, 0);
    }
#pragma unroll
    for (int q = 0; q < TN / 32; ++q) {
      int row = q * 32 + srow;
      int csw = sc ^ (row & 7);
      const short* gB = Bw + (size_t)(bn + row) * ldb + k0 + csw * 8;
      __builtin_amdgcn_global_load_lds(
          (const __attribute__((address_space(1))) void*)gB,
          (__attribute__((address_space(3))) void*)(&Bs[buf][q * 2048 + wid * 512]),
          16, 0, 0);
    }
  };

  const int nt = Kdim >> 6;
  STAGE(0, 0);
  int cur = 0;
  for (int ti = 0; ti < nt; ++ti) {
    __syncthreads();
    if (ti + 1 < nt) STAGE(cur ^ 1, (ti + 1) << 6);

    bf16x8 af[MREP][2], bfr[NREP][2];
#pragma unroll
    for (int m = 0; m < MREP; ++m)
#pragma unroll
      for (int kk = 0; kk < 2; ++kk) {
        int c16 = kk * 4 + khalf;
        int rowa = wr * WM + m * 16 + r16;
        af[m][kk] = *(const bf16x8*)(&As[cur][rowa * 64 + ((c16 ^ (rowa & 7)) << 3)]);
      }
#pragma unroll
    for (int nn = 0; nn < NREP; ++nn)
#pragma unroll
      for (int kk = 0; kk < 2; ++kk) {
        int c16 = kk * 4 + khalf;
        int rowb = wc * 64 + nn * 16 + r16;
        bfr[nn][kk] = *(const bf16x8*)(&Bs[cur][rowb * 64 + ((c16 ^ (rowb & 7)) << 3)]);
      }
#pragma unroll
    for (int kk = 0; kk < 2; ++kk)
#pragma unroll
      for (int m = 0; m < MREP; ++m)
#pragma unroll
        for (int nn = 0; nn < NREP; ++nn)
          acc[m][nn] = __builtin_amdgcn_mfma_f32_16x16x32_bf16(
              af[m][kk], bfr[nn][kk], acc[m][nn], 0, 0, 0);
    cur ^= 1;
  }

  const int rgrp = lane >> 4;
#pragma unroll
  for (int m = 0; m < MREP; ++m)
#pragma unroll
    for (int nn = 0; nn < NREP; ++nn) {
      int col = bn + wc * 64 + nn * 16 + r16;
#pragma unroll
      for (int rg = 0; rg < 4; ++rg) {
        int row = bm + wr * WM + m * 16 + rgrp * 4 + rg;
        float v = acc[m][nn][rg];
        if (MODE == 2) v += res[(size_t)row * ldres + col];
        if (MODE == 4) {
          v += bias[col];
          v = (v > 20.f) ? v : log1pf(expf(v));
        }
        if (MODE == 3 || MODE == 4)
          ((unsigned short*)Cv)[(size_t)row * ldc + col] = f2bf(v);
        else
          ((float*)Cv)[(size_t)row * ldc + col] = v;
      }
    }
}

// ---------------- split-K NT GEMM for x_proj (A bf16, B fp32) ----------------
#define BM 64
#define BN 64
#define BK 32
#define PADR 68

__global__ __launch_bounds__(256) void gemm_nt_sk(
    const unsigned short* __restrict__ A, int lda,
    const float* __restrict__ Bw, int ldb,
    float* __restrict__ part, int Ncols)
{
  __shared__ float as[BK][PADR];
  __shared__ float bs[BK][PADR];
  int bm = blockIdx.y * BM;
  int bn = blockIdx.x * BN;
  int sk = blockIdx.z;
  int t  = threadIdx.x;
  int tx = t & 15, ty = t >> 4;

  float acc[4][4] = {};

  int m0 = t >> 3;
  int kq = t & 7;
  const float4 z4 = {0.f, 0.f, 0.f, 0.f};

  for (int k0 = sk * KCH_; k0 < (sk + 1) * KCH_; k0 += BK) {
    u16x4 a0u = *(const u16x4*)(A + (size_t)(bm + m0) * lda + k0 + kq * 4);
    u16x4 a1u = *(const u16x4*)(A + (size_t)(bm + m0 + 32) * lda + k0 + kq * 4);
    float4 b0 = (bn + m0 < Ncols)
        ? *(const float4*)(Bw + (size_t)(bn + m0) * ldb + k0 + kq * 4) : z4;
    float4 b1 = (bn + m0 + 32 < Ncols)
        ? *(const float4*)(Bw + (size_t)(bn + m0 + 32) * ldb + k0 + kq * 4) : z4;
    as[kq * 4 + 0][m0] = bf2f(a0u[0]);  as[kq * 4 + 1][m0] = bf2f(a0u[1]);
    as[kq * 4 + 2][m0] = bf2f(a0u[2]);  as[kq * 4 + 3][m0] = bf2f(a0u[3]);
    as[kq * 4 + 0][m0 + 32] = bf2f(a1u[0]);  as[kq * 4 + 1][m0 + 32] = bf2f(a1u[1]);
    as[kq * 4 + 2][m0 + 32] = bf2f(a1u[2]);  as[kq * 4 + 3][m0 + 32] = bf2f(a1u[3]);
    bs[kq * 4 + 0][m0] = b0.x;  bs[kq * 4 + 1][m0] = b0.y;
    bs[kq * 4 + 2][m0] = b0.z;  bs[kq * 4 + 3][m0] = b0.w;
    bs[kq * 4 + 0][m0 + 32] = b1.x;  bs[kq * 4 + 1][m0 + 32] = b1.y;
    bs[kq * 4 + 2][m0 + 32] = b1.z;  bs[kq * 4 + 3][m0 + 32] = b1.w;
    __syncthreads();

#pragma unroll
    for (int kk = 0; kk < BK; ++kk) {
      float4 a4 = *(const float4*)&as[kk][ty * 4];
      float4 b4 = *(const float4*)&bs[kk][tx * 4];
      float ar[4] = {a4.x, a4.y, a4.z, a4.w};
      float br[4] = {b4.x, b4.y, b4.z, b4.w};
#pragma unroll
      for (int i = 0; i < 4; ++i)
#pragma unroll
        for (int j = 0; j < 4; ++j)
          acc[i][j] = fmaf(ar[i], br[j], acc[i][j]);
    }
    __syncthreads();
  }

  float* outp = part + (size_t)sk * M_ * XDW_;
#pragma unroll
  for (int i = 0; i < 4; ++i) {
    int r = bm + ty * 4 + i;
    int c = bn + tx * 4;
    float4 o = {acc[i][0], acc[i][1], acc[i][2], acc[i][3]};
    *(float4*)(outp + (size_t)r * XDW_ + c) = o;
  }
}

// reduce partials: xdbl[i] = sum_sk part[sk][i]; dt slice (cols 0..63) also -> bf16
__global__ __launch_bounds__(256) void reduce_sk(
    const float* __restrict__ part, float* __restrict__ xdbl,
    unsigned short* __restrict__ xdtb)
{
  int i = blockIdx.x * 256 + threadIdx.x;
  float s = 0.f;
#pragma unroll
  for (int sk = 0; sk < SK_; ++sk) s += part[(size_t)sk * M_ * XDW_ + i];
  xdbl[i] = s;
  int col = i & (XDW_ - 1);
  if (col < DTR_) xdtb[(size_t)(i >> 7) * DTR_ + col] = f2bf(s);
}

// ---------------- depthwise causal conv (K=4, bf16 in) + SiLU -> bf16 u ------
#define LCH 8
__global__ __launch_bounds__(256) void conv_silu_kernel(
    const unsigned short* __restrict__ xzb, const float* __restrict__ cw,
    const float* __restrict__ cb, unsigned short* __restrict__ ub)
{
  int d  = blockIdx.x * 256 + threadIdx.x;
  int l0 = blockIdx.y * LCH;
  int b  = blockIdx.z;
  float w0 = cw[d * 4 + 0], w1 = cw[d * 4 + 1];
  float w2 = cw[d * 4 + 2], w3 = cw[d * 4 + 3];
  float bias = cb[d];
  const unsigned short* xi = xzb + (size_t)(b * L_) * XZW_ + d;
  float x3 = (l0 >= 3) ? bf2f(xi[(size_t)(l0 - 3) * XZW_]) : 0.f;
  float x2 = (l0 >= 2) ? bf2f(xi[(size_t)(l0 - 2) * XZW_]) : 0.f;
  float x1 = (l0 >= 1) ? bf2f(xi[(size_t)(l0 - 1) * XZW_]) : 0.f;
#pragma unroll
  for (int l = l0; l < l0 + LCH; ++l) {
    float x0 = bf2f(xi[(size_t)l * XZW_]);
    float v = w0 * x3 + w1 * x2 + w2 * x1 + w3 * x0 + bias;
    float uu = v / (1.f + __expf(-v));
    ub[((size_t)(b * L_) + l) * DI_ + d] = f2bf(uu);
    x3 = x2; x2 = x1; x1 = x0;
  }
}

// ---------------- chunked selective scan (4 states/lane, 4 lanes/channel) ----
// dlt,u bf16; xdbl fp32. grid (DI/64, B, CH)
__global__ __launch_bounds__(256) void scan_p1(
    const unsigned short* __restrict__ dltb, const unsigned short* __restrict__ ub,
    const float* __restrict__ xdbl, const float* __restrict__ A_log,
    float* __restrict__ Pbuf, unsigned short* __restrict__ hend)
{
  int t = threadIdx.x;
  int ng = t & 3, dl = t >> 2;
  int d = blockIdx.x * 64 + dl;
  int b = blockIdx.y;
  int c = blockIdx.z;
  int l0 = c * CLEN_;
  float4 Al = *(const float4*)(A_log + d * NS_ + ng * 4);
  float A0 = -__expf(Al.x), A1 = -__expf(Al.y), A2 = -__expf(Al.z), A3 = -__expf(Al.w);
  float h0 = 0.f, h1 = 0.f, h2 = 0.f, h3 = 0.f, S = 0.f;
  const unsigned short* dp = dltb + ((size_t)(b * L_) + l0) * DI_ + d;
  const unsigned short* up = ub   + ((size_t)(b * L_) + l0) * DI_ + d;
  const float* xp = xdbl + ((size_t)(b * L_) + l0) * XDW_ + DTR_ + ng * 4;
  float dv = bf2f(dp[0]), uv = bf2f(up[0]);
  float4 Bv = *(const float4*)xp;
  for (int l = 0; l < CLEN_; ++l) {
    int ln = (l + 1 < CLEN_) ? l + 1 : l;
    float dv_n = bf2f(dp[(size_t)ln * DI_]);
    float uv_n = bf2f(up[(size_t)ln * DI_]);
    float4 Bv_n = *(const float4*)(xp + (size_t)ln * XDW_);
    float dvu = dv * uv;
    h0 = __expf(dv * A0) * h0 + dvu * Bv.x;
    h1 = __expf(dv * A1) * h1 + dvu * Bv.y;
    h2 = __expf(dv * A2) * h2 + dvu * Bv.z;
    h3 = __expf(dv * A3) * h3 + dvu * Bv.w;
    S += dv;
    dv = dv_n; uv = uv_n; Bv = Bv_n;
  }
  size_t i = ((size_t)((b * CH_ + c) * DI_) + d) * NS_ + ng * 4;
  float4 P; P.x = __expf(S * A0); P.y = __expf(S * A1);
  P.z = __expf(S * A2); P.w = __expf(S * A3);
  u16x4 H; H[0] = f2bf(h0); H[1] = f2bf(h1); H[2] = f2bf(h2); H[3] = f2bf(h3);
  *(float4*)(Pbuf + i) = P;
  *(u16x4*)(hend + i) = H;
}

__global__ __launch_bounds__(256) void scan_p2(
    float* __restrict__ Pbuf, const unsigned short* __restrict__ hend)
{
  int tid = blockIdx.x * 256 + threadIdx.x;   // over B*DI*NS = 65536
  int n = tid & 15;
  int d = (tid >> 4) & (DI_ - 1);
  int b = tid >> 15;
  float h = 0.f;
  for (int c = 0; c < CH_; ++c) {
    size_t i = ((size_t)((b * CH_ + c) * DI_) + d) * NS_ + n;
    float Pv = Pbuf[i];
    float he = bf2f(hend[i]);
    Pbuf[i] = h;
    h = Pv * h + he;
  }
}

__global__ __launch_bounds__(256) void scan_p3(
    const unsigned short* __restrict__ dltb, const unsigned short* __restrict__ ub,
    const float* __restrict__ xdbl, const float* __restrict__ A_log,
    const float* __restrict__ hin, const unsigned short* __restrict__ xzb,
    const float* __restrict__ Dp, unsigned short* __restrict__ yb)
{
  int t = threadIdx.x;
  int ng = t & 3, dl = t >> 2;
  int d = blockIdx.x * 64 + dl;
  int b = blockIdx.y;
  int c = blockIdx.z;
  int l0 = c * CLEN_;
  float4 Al = *(const float4*)(A_log + d * NS_ + ng * 4);
  float A0 = -__expf(Al.x), A1 = -__expf(Al.y), A2 = -__expf(Al.z), A3 = -__expf(Al.w);
  size_t i0 = ((size_t)((b * CH_ + c) * DI_) + d) * NS_ + ng * 4;
  float4 hv = *(const float4*)(hin + i0);
  float h0 = hv.x, h1 = hv.y, h2 = hv.z, h3 = hv.w;
  float Dd = Dp[d];
  const unsigned short* dp = dltb + ((size_t)(b * L_) + l0) * DI_ + d;
  const unsigned short* up = ub   + ((size_t)(b * L_) + l0) * DI_ + d;
  const float* xp = xdbl + ((size_t)(b * L_) + l0) * XDW_ + DTR_ + ng * 4;
  const unsigned short* zp = xzb + ((size_t)(b * L_) + l0) * XZW_ + DI_ + d;
  unsigned short* yp = yb + ((size_t)(b * L_) + l0) * DI_ + d;
  float dv = bf2f(dp[0]), uv = bf2f(up[0]);
  float4 Bv = *(const float4*)xp;
  float4 Cv = *(const float4*)(xp + NS_);
  for (int l = 0; l < CLEN_; ++l) {
    int ln = (l + 1 < CLEN_) ? l + 1 : l;
    float dv_n = bf2f(dp[(size_t)ln * DI_]);
    float uv_n = bf2f(up[(size_t)ln * DI_]);
    float4 Bv_n = *(const float4*)(xp + (size_t)ln * XDW_);
    float4 Cv_n = *(const float4*)(xp + (size_t)ln * XDW_ + NS_);
    float dvu = dv * uv;
    h0 = __expf(dv * A0) * h0 + dvu * Bv.x;
    h1 = __expf(dv * A1) * h1 + dvu * Bv.y;
    h2 = __expf(dv * A2) * h2 + dvu * Bv.z;
    h3 = __expf(dv * A3) * h3 + dvu * Bv.w;
    float py = h0 * Cv.x + h1 * Cv.y + h2 * Cv.z + h3 * Cv.w;
    py += __shfl_xor(py, 1);
    py += __shfl_xor(py, 2);
    if (ng == 0) {
      float z = bf2f(zp[(size_t)l * XZW_]);
      float zs = z / (1.f + __expf(-z));
      yp[(size_t)l * DI_] = f2bf((py + uv * Dd) * zs);
    }
    dv = dv_n; uv = uv_n; Bv = Bv_n; Cv = Cv_n;
  }
}

extern "C" void kernel_launch(void* const* d_in, const int* in_sizes, int n_in,
                              void* d_out, int out_size, void* d_ws, size_t ws_size,
                              hipStream_t stream)
{
  const float* x         = (const float*)d_in[0];
  const float* ln_g      = (const float*)d_in[1];
  const float* ln_b      = (const float*)d_in[2];
  const float* in_proj_w = (const float*)d_in[3];
  const float* conv_w    = (const float*)d_in[4];
  const float* conv_b    = (const float*)d_in[5];
  const float* x_proj_w  = (const float*)d_in[6];
  const float* dt_proj_w = (const float*)d_in[7];
  const float* dt_proj_b = (const float*)d_in[8];
  const float* A_log     = (const float*)d_in[9];
  const float* Dp        = (const float*)d_in[10];
  const float* out_proj_w= (const float*)d_in[11];
  float* out = (float*)d_out;

  float* ws = (float*)d_ws;
  // no aliasing — ws_size ~268 MB, we use 89.7 MB
  unsigned short* xzb  = (unsigned short*)ws;              // [0, 4194304)
  unsigned short* ub   = (unsigned short*)(ws + 4194304);  // [4194304, 6291456)
  float* xdbl          = ws + 6291456;                     // [6291456, 6553600)
  unsigned short* dltb = (unsigned short*)(ws + 6553600);  // [6553600, 8650752)
  unsigned short* xdtb = (unsigned short*)(ws + 8650752);  // [8650752, 8716288)
  unsigned short* dtwb = (unsigned short*)(ws + 8716288);  // [8716288, 8781824)
  unsigned short* xnb  = (unsigned short*)(ws + 8781824);  // [8781824, 9830400)
  unsigned short* winb = (unsigned short*)(ws + 9830400);  // [9830400, 11927552)
  unsigned short* woutb= (unsigned short*)(ws + 11927552); // [11927552, 12976128)
  unsigned short* yb   = (unsigned short*)(ws + 12976128); // [12976128, 14024704)
  float* skpart        = ws + 14024704;                    // [14024704, 16121856)
  float* Pbuf          = ws + 16121856;                    // [16121856, 20316160)
  unsigned short* hendb= (unsigned short*)(ws + 20316160); // [20316160, 22413312)

  // 1. LayerNorm -> bf16
  ln_kernel<<<M_, 256, 0, stream>>>(x, ln_g, ln_b, xnb);

  // 2. fused weight conversions fp32 -> bf16 (in_proj_w | out_proj_w | dt_proj_w)
  f2bf3_kernel<<<(1048576 + 524288 + 32768 + 255) / 256, 256, 0, stream>>>(
      (const float4*)in_proj_w, (u16x4*)winb, 1048576,
      (const float4*)out_proj_w, (u16x4*)woutb, 524288,
      (const float4*)dt_proj_w, (u16x4*)dtwb, 32768);

  // 3. in_proj (MFMA, dbuf, bf16 out): xzb = xn @ in_proj_w^T
  gemm_mfma<3, 128><<<dim3(XZW_ / 128, M_ / 128), 256, 0, stream>>>(
      (const short*)xnb, DM_, (const short*)winb, DM_, xzb, XZW_, DM_,
      nullptr, 0, nullptr);

  // 4. conv + silu -> u (bf16)
  conv_silu_kernel<<<dim3(DI_ / 256, L_ / LCH, B_), 256, 0, stream>>>(
      xzb, conv_w, conv_b, ub);

  // 5. x_proj split-K (A bf16) + reduce (emits fp32 xdbl + bf16 dt slice)
  gemm_nt_sk<<<dim3(XDW_ / BN, M_ / BM, SK_), 256, 0, stream>>>(
      ub, DI_, x_proj_w, DI_, skpart, 96);
  reduce_sk<<<(M_ * XDW_) / 256, 256, 0, stream>>>(skpart, xdbl, xdtb);

  // 6. dt_proj (MFMA, K=64, fused bias+softplus -> bf16)
  gemm_mfma<4, 128><<<dim3(DI_ / 128, M_ / 128), 256, 0, stream>>>(
      (const short*)xdtb, DTR_, (const short*)dtwb, DTR_, dltb, DI_, DTR_,
      nullptr, 0, dt_proj_b);

  // 7. chunked scan (CH=64)
  scan_p1<<<dim3(DI_ / 64, B_, CH_), 256, 0, stream>>>(dltb, ub, xdbl, A_log, Pbuf, hendb);
  scan_p2<<<(B_ * DI_ * NS_) / 256, 256, 0, stream>>>(Pbuf, hendb);
  scan_p3<<<dim3(DI_ / 64, B_, CH_), 256, 0, stream>>>(
      dltb, ub, xdbl, A_log, Pbuf, xzb, Dp, yb);

  // 8. out_proj (MFMA, dbuf, TN=64) + residual
  gemm_mfma<2, 64><<<dim3(DM_ / 64, M_ / 128), 256, 0, stream>>>(
      (const short*)yb, DI_, (const short*)woutb, DI_, out, DM_, DI_, x, DM_, nullptr);
}